// Round 6
// baseline (2755.591 us; speedup 1.0000x reference)
//
#include <hip/hip_runtime.h>
#include <math.h>

#define THREADS 256

__device__ __forceinline__ float silu_f(float v) {
    return v / (1.f + __expf(-v));
}

// ---------------------------------------------------------------------------
// Weight transpose: [co][ci][k2] -> [ci][k2][co]  (co contiguous)
// Also used per-half for the 36-out convs and per-group for deform-conv.
// ---------------------------------------------------------------------------
struct TEnt { const float* src; int dst; int cin; int cout; int k2; int base; int n; };
struct TTab { TEnt e[27]; int total; };

__global__ __launch_bounds__(THREADS)
void transpose_w_k(TTab t, float* __restrict__ tw) {
    const int i = blockIdx.x * THREADS + threadIdx.x;
    if (i >= t.total) return;
    int j = 0;
    while (i >= t.e[j].base + t.e[j].n) ++j;
    const TEnt e = t.e[j];
    const int local = i - e.base;
    const int co  = local % e.cout;
    const int tmp = local / e.cout;
    const int k   = tmp % e.k2;
    const int ci  = tmp / e.k2;
    tw[e.dst + local] = e.src[(co * e.cin + ci) * e.k2 + k];
}

// ---------------------------------------------------------------------------
// Direct conv2d, stride 1, pad (KS-1)/2, NCHW. PX=4 consecutive x-pixels per
// thread (x0 % 4 == 0 -> aligned float4 loads/stores), all COUT channels in
// registers. Transposed weights staged into LDS in CCH-channel chunks,
// CO_S-padded so weight reads are b128 broadcasts. 2-stage weight pipeline:
// tap t+1's ds_reads issue inside region t; sched_barrier(0) after each
// tap's FMA block pins the live range (round-4 lesson: unconstrained
// hoisting -> 900-float live range -> spill).
// ---------------------------------------------------------------------------
template<int CIN, int COUT, int KS, bool ACT, int CCH = CIN>
__global__ __launch_bounds__(THREADS)
void conv_k(const float* __restrict__ in, const float* __restrict__ wt,
            const float* __restrict__ bias, float* __restrict__ out,
            int H, int lw, int bs_in, int bs_out)
{
    constexpr int PAD = (KS - 1) / 2;
    constexpr int K2 = KS * KS;
    constexpr int PX = 4;
    constexpr int CO_S = (COUT + 3) & ~3;
    constexpr int WQ = CO_S / 4;
    constexpr int NCH = CIN / CCH;
    __shared__ float sw[CCH * K2 * CO_S];

    const int W = 1 << lw;
    const int total = H << lw;
    const int idx = (blockIdx.x * THREADS + threadIdx.x) * PX;
    const float* ip0 = in + (size_t)blockIdx.y * bs_in;
    float* op = out + (size_t)blockIdx.y * bs_out;
    const int x0 = idx & (W - 1);               // multiple of 4
    const int y  = idx >> lw;

    float acc[COUT][PX];
#pragma unroll
    for (int co = 0; co < COUT; ++co) {
        const float b = bias[co];               // uniform address -> s_load
#pragma unroll
        for (int j = 0; j < PX; ++j) acc[co][j] = b;
    }

    for (int ch = 0; ch < NCH; ++ch) {
        const float* src = wt + (size_t)ch * (CCH * K2 * COUT);
        for (int i = threadIdx.x; i < CCH * K2 * COUT; i += THREADS) {
            const int co = i % COUT;
            const int rest = i / COUT;
            sw[rest * CO_S + co] = src[i];
        }
        __syncthreads();

#pragma unroll 1
        for (int cl = 0; cl < CCH; ++cl) {
            const float* __restrict__ row0 = ip0 + (size_t)(ch * CCH + cl) * total;
            // ---- preload all KS rows, aligned float4 ----
            float r[KS][PX + KS - 1];
#pragma unroll
            for (int ky = 0; ky < KS; ++ky) {
                const int yy = y + ky - PAD;
                const bool vy = (unsigned)yy < (unsigned)H;
                const float* __restrict__ rp = row0 + (yy << lw);
                if (KS == 5) {
                    const float4 z = make_float4(0.f, 0.f, 0.f, 0.f);
                    float4 a = (vy && x0 >= 4)     ? *reinterpret_cast<const float4*>(rp + x0 - 4) : z;
                    float4 b = vy                  ? *reinterpret_cast<const float4*>(rp + x0)     : z;
                    float4 c = (vy && x0 + 8 <= W) ? *reinterpret_cast<const float4*>(rp + x0 + 4) : z;
                    r[ky][0] = a.z; r[ky][1] = a.w;
                    r[ky][2] = b.x; r[ky][3] = b.y; r[ky][4] = b.z; r[ky][5] = b.w;
                    r[ky][6] = c.x; r[ky][7] = c.y;
                } else {
                    const float4 z = make_float4(0.f, 0.f, 0.f, 0.f);
                    float4 b = vy ? *reinterpret_cast<const float4*>(rp + x0) : z;
                    r[ky][0] = (vy && x0 > 0)      ? rp[x0 - 1] : 0.f;
                    r[ky][1] = b.x; r[ky][2] = b.y; r[ky][3] = b.z; r[ky][4] = b.w;
                    r[ky][5] = (vy && x0 + 4 < W)  ? rp[x0 + 4] : 0.f;
                }
            }
            // ---- FMA sweep, 2-stage weight pipeline over K2 taps ----
            const float* __restrict__ wbase = &sw[cl * K2 * CO_S];
            float4 wb[2][WQ];
#pragma unroll
            for (int q = 0; q < WQ; ++q)
                wb[0][q] = reinterpret_cast<const float4*>(wbase)[q];
#pragma unroll
            for (int t = 0; t < K2; ++t) {
                const int cur = t & 1;
                if (t + 1 < K2) {
                    const float4* __restrict__ nx =
                        reinterpret_cast<const float4*>(wbase + (t + 1) * CO_S);
#pragma unroll
                    for (int q = 0; q < WQ; ++q) wb[cur ^ 1][q] = nx[q];
                }
                const int ky = t / KS, kx = t % KS;
#pragma unroll
                for (int q = 0; q < WQ; ++q) {
                    const float4 w = wb[cur][q];
                    const float wc[4] = {w.x, w.y, w.z, w.w};
#pragma unroll
                    for (int c = 0; c < 4; ++c) {
                        const int co = 4 * q + c;
                        if (co < COUT) {
#pragma unroll
                            for (int j = 0; j < PX; ++j)
                                acc[co][j] = fmaf(r[ky][kx + j], wc[c], acc[co][j]);
                        }
                    }
                }
                __builtin_amdgcn_sched_barrier(0);
            }
        }
        if (NCH > 1) __syncthreads();
    }

#pragma unroll
    for (int co = 0; co < COUT; ++co) {
        float4 v;
        v.x = ACT ? silu_f(acc[co][0]) : acc[co][0];
        v.y = ACT ? silu_f(acc[co][1]) : acc[co][1];
        v.z = ACT ? silu_f(acc[co][2]) : acc[co][2];
        v.w = ACT ? silu_f(acc[co][3]) : acc[co][3];
        *reinterpret_cast<float4*>(op + (size_t)co * total + idx) = v;
    }
}

// ---------------------------------------------------------------------------
// DeformConv2d: 3x3, stride 1, pad 1, no bias. groups=2, offset groups=2.
// Per-group transposed weights [c][k][col] staged into LDS.
// offset layout: [OG=2][K=9][2(dy,dx)][H][W]
// ---------------------------------------------------------------------------
template<int CIN, int COUT>
__global__ __launch_bounds__(THREADS)
void dconv_k(const float* __restrict__ in, const float* __restrict__ off,
             const float* __restrict__ twg0, const float* __restrict__ twg1,
             float* __restrict__ out,
             int H, int lw, int bs_in, int bs_off, int bs_out)
{
    constexpr int K = 9;
    constexpr int OG = 2;
    constexpr int COG = CIN / OG;
    constexpr int COUTG = COUT / 2;
    constexpr int NWG = COG * K * COUTG;
    __shared__ float sw[2 * NWG];
    for (int i = threadIdx.x; i < 2 * NWG; i += THREADS)
        sw[i] = (i < NWG) ? twg0[i] : twg1[i - NWG];
    __syncthreads();

    const int W = 1 << lw;
    const int total = H << lw;
    const int idx = blockIdx.x * THREADS + threadIdx.x;
    const float* ip0 = in + (size_t)blockIdx.y * bs_in;
    const float* offp = off + (size_t)blockIdx.y * bs_off;
    float* op = out + (size_t)blockIdx.y * bs_out;
    const int x = idx & (W - 1);
    const int y = idx >> lw;

    float acc[COUT];
#pragma unroll
    for (int co = 0; co < COUT; ++co) acc[co] = 0.f;

#pragma unroll
    for (int og = 0; og < OG; ++og) {
#pragma unroll
        for (int k = 0; k < K; ++k) {
            const int ki = k / 3 - 1;
            const int kj = k % 3 - 1;
            const float dy = offp[(size_t)(((og * K + k) * 2 + 0)) * total + idx];
            const float dx = offp[(size_t)(((og * K + k) * 2 + 1)) * total + idx];
            const float py = dy + (float)(y + ki);
            const float px = dx + (float)(x + kj);
            const float y0f = floorf(py), x0f = floorf(px);
            const float ly = py - y0f, lx = px - x0f;
            const int y0 = (int)y0f, x0 = (int)x0f;
            const int y1 = y0 + 1, x1 = x0 + 1;
            const bool vy0 = (unsigned)y0 < (unsigned)H;
            const bool vy1 = (unsigned)y1 < (unsigned)H;
            const bool vx0 = (unsigned)x0 < (unsigned)W;
            const bool vx1 = (unsigned)x1 < (unsigned)W;
            const int cy0 = min(max(y0, 0), H - 1), cy1 = min(max(y1, 0), H - 1);
            const int cx0 = min(max(x0, 0), W - 1), cx1 = min(max(x1, 0), W - 1);
            const int i00 = (cy0 << lw) + cx0, i01 = (cy0 << lw) + cx1;
            const int i10 = (cy1 << lw) + cx0, i11 = (cy1 << lw) + cx1;
            const float f00 = (vy0 && vx0) ? (1.f - ly) * (1.f - lx) : 0.f;
            const float f01 = (vy0 && vx1) ? (1.f - ly) * lx : 0.f;
            const float f10 = (vy1 && vx0) ? ly * (1.f - lx) : 0.f;
            const float f11 = (vy1 && vx1) ? ly * lx : 0.f;
            const float* swg = &sw[og * NWG];
#pragma unroll
            for (int c = 0; c < COG; ++c) {
                const float* __restrict__ ip = ip0 + (size_t)(og * COG + c) * total;
                const float v = f00 * ip[i00] + f01 * ip[i01]
                              + f10 * ip[i10] + f11 * ip[i11];
                const float* __restrict__ wr = &swg[(c * K + k) * COUTG];
#pragma unroll
                for (int col = 0; col < COUTG; ++col)
                    acc[og * COUTG + col] = fmaf(v, wr[col], acc[og * COUTG + col]);
            }
        }
    }

#pragma unroll
    for (int co = 0; co < COUT; ++co)
        op[(size_t)co * total + idx] = acc[co];
}

// 2x2 average pool. n = C*Ho*Wo, lt = log2(Ho*Wo), lwo = log2(Wo).
__global__ __launch_bounds__(THREADS)
void avgpool_k(const float* __restrict__ in, float* __restrict__ out,
               int n, int lt, int lwo, int bsi, int bso)
{
    const int idx = blockIdx.x * THREADS + threadIdx.x;
    if (idx >= n) return;
    const float* ip0 = in + (size_t)blockIdx.y * bsi;
    float* op = out + (size_t)blockIdx.y * bso;
    const int c = idx >> lt;
    const int r = idx & ((1 << lt) - 1);
    const int oy = r >> lwo;
    const int ox = r & ((1 << lwo) - 1);
    const int Wi = 2 << lwo;
    const float* ip = ip0 + ((size_t)c << (lt + 2)) + ((size_t)(2 * oy) << (lwo + 1)) + 2 * ox;
    const float2 t = *reinterpret_cast<const float2*>(ip);
    const float2 b = *reinterpret_cast<const float2*>(ip + Wi);
    op[idx] = 0.25f * (t.x + t.y + b.x + b.y);
}

// Bilinear 2x upsample, align_corners=True.
__global__ __launch_bounds__(THREADS)
void up2x_k(const float* __restrict__ in, float* __restrict__ out,
            int n, int lt, int lwo, int Hin, int bsi, int bso)
{
    const int idx = blockIdx.x * THREADS + threadIdx.x;
    if (idx >= n) return;
    const float* ip0 = in + (size_t)blockIdx.y * bsi;
    float* op = out + (size_t)blockIdx.y * bso;
    const int c = idx >> lt;
    const int r = idx & ((1 << lt) - 1);
    const int oy = r >> lwo;
    const int ox = r & ((1 << lwo) - 1);
    const int W = 1 << (lwo - 1);
    const int H = Hin;
    const float s = (float)(H - 1) / (float)(2 * H - 1);
    const float fy = (float)oy * s;
    const float fx = (float)ox * s;
    const int y0 = (int)fy;
    const int x0 = (int)fx;
    const int y1 = min(y0 + 1, H - 1);
    const int x1 = min(x0 + 1, W - 1);
    const float wy = fy - (float)y0;
    const float wx = fx - (float)x0;
    const float* ip = ip0 + ((size_t)c << (lt - 2));
    const float v00 = ip[y0 * W + x0], v01 = ip[y0 * W + x1];
    const float v10 = ip[y1 * W + x0], v11 = ip[y1 * W + x1];
    op[idx] = (v00 * (1.f - wy) + v10 * wy) * (1.f - wx)
            + (v01 * (1.f - wy) + v11 * wy) * wx;
}

// strided batched d2d copy (float4 granularity)
__global__ __launch_bounds__(THREADS)
void copy_k(float4* __restrict__ dst, const float4* __restrict__ src,
            int n4, int bsd, int bss)
{
    const int i = blockIdx.x * THREADS + threadIdx.x;
    if (i >= n4) return;
    dst[(size_t)blockIdx.y * bsd + i] = src[(size_t)blockIdx.y * bss + i];
}

// ---------------------------------------------------------------------------

extern "C" void kernel_launch(void* const* d_in, const int* in_sizes, int n_in,
                              void* d_out, int out_size, void* d_ws, size_t ws_size,
                              hipStream_t stream) {
    const float* x      = (const float*)d_in[0];
    const float* eo1_b1 = (const float*)d_in[2];
    const float* eo1_b2 = (const float*)d_in[4];
    const float* c1d_b1 = (const float*)d_in[7];
    const float* c1d_b2 = (const float*)d_in[9];
    const float* eo2_b1 = (const float*)d_in[11];
    const float* eo2_b2 = (const float*)d_in[13];
    const float* c2d_b1 = (const float*)d_in[16];
    const float* c2d_b2 = (const float*)d_in[18];
    const float* eo3_b1 = (const float*)d_in[20];
    const float* eo3_b2 = (const float*)d_in[22];
    const float* c3d_b1 = (const float*)d_in[25];
    const float* c3d_b2 = (const float*)d_in[27];
    const float* up2_b  = (const float*)d_in[29];
    const float* c2u_b1 = (const float*)d_in[31];
    const float* c2u_b2 = (const float*)d_in[33];
    const float* up1_b  = (const float*)d_in[35];
    const float* c1u_b1 = (const float*)d_in[37];
    const float* c1u_b2 = (const float*)d_in[39];

    float* out = (float*)d_out;
    float* wsf = (float*)d_ws;

    constexpr int H1 = 512, A1 = H1 * H1;
    constexpr int H2 = 256, A2 = H2 * H2;
    constexpr int H3 = 128, A3 = H3 * H3;
    constexpr int TW_FLOATS = 81920;
    constexpr int SLOT = 70 * A1 + 24 * A2;

    // ---- transposed-weight table: 21 conv entries (36-out convs split into
    //      two 18-out halves) + 6 dconv group entries ----
    const int widx[21]  = {1, 3, 3, 6, 8, 10, 12, 12, 15, 17, 19, 21, 21, 24, 26, 28, 30, 32, 34, 36, 38};
    const int wcin[21]  = {4, 18, 18, 2, 4, 8, 18, 18, 8, 12, 16, 18, 18, 16, 14, 12, 28, 16, 8, 16, 8};
    const int wcout[21] = {18, 18, 18, 4, 8, 18, 18, 18, 12, 16, 18, 18, 18, 14, 12, 12, 16, 8, 8, 8, 2};
    const int wk2[21]   = {25, 25, 25, 9, 9, 25, 25, 25, 9, 9, 25, 25, 25, 9, 9, 9, 9, 9, 9, 9, 9};
    const int wsoff[21] = {0, 0, 8100, 0, 0, 0, 0, 8100, 0, 0, 0, 0, 8100, 0, 0, 0, 0, 0, 0, 0, 0};
    TTab tab;
    const float* tw[27];
    int off = 0, base = 0;
    for (int i = 0; i < 21; ++i) {
        const int n = wcin[i] * wcout[i] * wk2[i];
        tab.e[i].src = (const float*)d_in[widx[i]] + wsoff[i];
        tab.e[i].dst = off; tab.e[i].cin = wcin[i]; tab.e[i].cout = wcout[i];
        tab.e[i].k2 = wk2[i]; tab.e[i].base = base; tab.e[i].n = n;
        tw[i] = wsf + off;
        off = (off + n + 63) & ~63;
        base += n;
    }
    const int didx[3]   = {5, 14, 23};
    const int dcoutg[3] = {1, 4, 8};
    const int dcpg[3]   = {2, 4, 8};
    for (int i = 0; i < 3; ++i) {
        for (int g = 0; g < 2; ++g) {
            const int e = 21 + 2 * i + g;
            const int n = dcoutg[i] * dcpg[i] * 9;
            tab.e[e].src = (const float*)d_in[didx[i]] + (size_t)g * n;
            tab.e[e].dst = off; tab.e[e].cin = dcpg[i]; tab.e[e].cout = dcoutg[i];
            tab.e[e].k2 = 9; tab.e[e].base = base; tab.e[e].n = n;
            tw[e] = wsf + off;
            off = (off + n + 63) & ~63;
            base += n;
        }
    }
    tab.total = base;
    transpose_w_k<<<(base + THREADS - 1) / THREADS, THREADS, 0, stream>>>(tab, wsf);

    int B = 4;
    while (B > 1 && ws_size < ((size_t)TW_FLOATS + (size_t)B * SLOT) * sizeof(float)) B >>= 1;

    auto run_all = [&](int Bc, float* slot, int SB,
                       const float* xin, int xbs, float* outp, int obs) {
        float* S0 = slot;                // 36*A1
        float* S1 = S0 + 36 * A1;        // 18*A1
        float* S2 = S1 + 18 * A1;        //  8*A1
        float* P  = S2 + 8 * A1;         //  8*A2
        float* L1 = P + 8 * A2;          //  8*A1  (conv1_d skip)
        float* L2 = L1 + 8 * A1;         // 16*A2  (conv2_d skip)
        auto g4 = [&](int n) { return dim3(n / (4 * THREADS), Bc); };
        auto g1 = [&](int n) { return dim3((n + THREADS - 1) / THREADS, Bc); };

        // ---- level 1 down ----
        conv_k<4, 18, 5, false><<<g4(A1), THREADS, 0, stream>>>(xin, tw[0], eo1_b1, S1, H1, 9, xbs, SB);
        conv_k<18, 18, 5, false, 6><<<g4(A1), THREADS, 0, stream>>>(S1, tw[1], eo1_b2, S0, H1, 9, SB, SB);
        conv_k<18, 18, 5, false, 6><<<g4(A1), THREADS, 0, stream>>>(S1, tw[2], eo1_b2 + 18, S0 + 18 * A1, H1, 9, SB, SB);
        dconv_k<4, 2><<<g1(A1), THREADS, 0, stream>>>(xin, S0, tw[21], tw[22], S2, H1, 9, xbs, SB, SB);
        conv_k<2, 4, 3, true><<<g4(A1), THREADS, 0, stream>>>(S2, tw[3], c1d_b1, S1, H1, 9, SB, SB);
        conv_k<4, 8, 3, true><<<g4(A1), THREADS, 0, stream>>>(S1, tw[4], c1d_b2, L1, H1, 9, SB, SB);
        avgpool_k<<<g1(8 * A2), THREADS, 0, stream>>>(L1, P, 8 * A2, 16, 8, SB, SB);

        // ---- level 2 down ----
        conv_k<8, 18, 5, false><<<g4(A2), THREADS, 0, stream>>>(P, tw[5], eo2_b1, S1, H2, 8, SB, SB);
        conv_k<18, 18, 5, false, 6><<<g4(A2), THREADS, 0, stream>>>(S1, tw[6], eo2_b2, S0, H2, 8, SB, SB);
        conv_k<18, 18, 5, false, 6><<<g4(A2), THREADS, 0, stream>>>(S1, tw[7], eo2_b2 + 18, S0 + 18 * A2, H2, 8, SB, SB);
        dconv_k<8, 8><<<g1(A2), THREADS, 0, stream>>>(P, S0, tw[23], tw[24], S2, H2, 8, SB, SB, SB);
        conv_k<8, 12, 3, true><<<g4(A2), THREADS, 0, stream>>>(S2, tw[8], c2d_b1, S1, H2, 8, SB, SB);
        conv_k<12, 16, 3, true><<<g4(A2), THREADS, 0, stream>>>(S1, tw[9], c2d_b2, L2, H2, 8, SB, SB);
        avgpool_k<<<g1(16 * A3), THREADS, 0, stream>>>(L2, P, 16 * A3, 14, 7, SB, SB);

        // ---- level 3 (bottleneck) ----
        conv_k<16, 18, 5, false, 8><<<g4(A3), THREADS, 0, stream>>>(P, tw[10], eo3_b1, S1, H3, 7, SB, SB);
        conv_k<18, 18, 5, false, 6><<<g4(A3), THREADS, 0, stream>>>(S1, tw[11], eo3_b2, S0, H3, 7, SB, SB);
        conv_k<18, 18, 5, false, 6><<<g4(A3), THREADS, 0, stream>>>(S1, tw[12], eo3_b2 + 18, S0 + 18 * A3, H3, 7, SB, SB);
        dconv_k<16, 16><<<g1(A3), THREADS, 0, stream>>>(P, S0, tw[25], tw[26], S2, H3, 7, SB, SB, SB);
        conv_k<16, 14, 3, true><<<g4(A3), THREADS, 0, stream>>>(S2, tw[13], c3d_b1, S1, H3, 7, SB, SB);
        conv_k<14, 12, 3, true><<<g4(A3), THREADS, 0, stream>>>(S1, tw[14], c3d_b2, S2, H3, 7, SB, SB);

        // ---- up path level 2 ----
        up2x_k<<<g1(12 * A2), THREADS, 0, stream>>>(S2, S0, 12 * A2, 16, 8, H3, SB, SB);
        conv_k<12, 12, 3, true><<<g4(A2), THREADS, 0, stream>>>(S0, tw[15], up2_b, S1, H2, 8, SB, SB);
        copy_k<<<g1(4 * A2), THREADS, 0, stream>>>((float4*)(S1 + 12 * A2), (const float4*)L2,
                                                   4 * A2, SB / 4, SB / 4);
        conv_k<28, 16, 3, true><<<g4(A2), THREADS, 0, stream>>>(S1, tw[16], c2u_b1, S0, H2, 8, SB, SB);
        conv_k<16, 8, 3, true><<<g4(A2), THREADS, 0, stream>>>(S0, tw[17], c2u_b2, S2, H2, 8, SB, SB);

        // ---- up path level 1 ----
        up2x_k<<<g1(8 * A1), THREADS, 0, stream>>>(S2, S0, 8 * A1, 18, 9, H2, SB, SB);
        conv_k<8, 8, 3, true><<<g4(A1), THREADS, 0, stream>>>(S0, tw[18], up1_b, S1, H1, 9, SB, SB);
        copy_k<<<g1(2 * A1), THREADS, 0, stream>>>((float4*)(S1 + 8 * A1), (const float4*)L1,
                                                   2 * A1, SB / 4, SB / 4);
        conv_k<16, 8, 3, true><<<g4(A1), THREADS, 0, stream>>>(S1, tw[19], c1u_b1, S0, H1, 9, SB, SB);
        conv_k<8, 2, 3, true><<<g4(A1), THREADS, 0, stream>>>(S0, tw[20], c1u_b2, outp, H1, 9, SB, obs);
    };

    for (int g = 0; g < 4; g += B)
        run_all(B, wsf + TW_FLOATS, SLOT,
                x + (size_t)g * 4 * A1, 4 * A1,
                out + (size_t)g * 2 * A1, 2 * A1);
}

// Round 7
// 2043.674 us; speedup vs baseline: 1.3484x; 1.3484x over previous
//
#include <hip/hip_runtime.h>
#include <math.h>

#define THREADS 256

__device__ __forceinline__ float silu_f(float v) {
    return v / (1.f + __expf(-v));
}

// ---------------------------------------------------------------------------
// Weight transpose: [co][ci][k2] -> [ci][k2][co]  (co contiguous)
// Also used per-half for the 36-out convs and per-group for deform-conv.
// ---------------------------------------------------------------------------
struct TEnt { const float* src; int dst; int cin; int cout; int k2; int base; int n; };
struct TTab { TEnt e[27]; int total; };

__global__ __launch_bounds__(THREADS)
void transpose_w_k(TTab t, float* __restrict__ tw) {
    const int i = blockIdx.x * THREADS + threadIdx.x;
    if (i >= t.total) return;
    int j = 0;
    while (i >= t.e[j].base + t.e[j].n) ++j;
    const TEnt e = t.e[j];
    const int local = i - e.base;
    const int co  = local % e.cout;
    const int tmp = local / e.cout;
    const int k   = tmp % e.k2;
    const int ci  = tmp / e.k2;
    tw[e.dst + local] = e.src[(co * e.cin + ci) * e.k2 + k];
}

// ---------------------------------------------------------------------------
// Direct conv2d, stride 1, pad (KS-1)/2, NCHW. PX=2 pixels per thread,
// all COUT channels in registers. ALL weights staged once into LDS
// (CO_S-padded -> float4/b128 broadcast reads). Per-tap sched_barrier(0)
// pins live ranges (round-4 lesson: unconstrained hoisting -> spill).
// Occupancy target: VGPR<=~110 (4+ waves/SIMD), grid 4 blocks/CU at 512^2.
// ---------------------------------------------------------------------------
template<int CIN, int COUT, int KS, bool ACT>
__global__ __launch_bounds__(THREADS)
void conv_k(const float* __restrict__ in, const float* __restrict__ wt,
            const float* __restrict__ bias, float* __restrict__ out,
            int H, int lw, int bs_in, int bs_out)
{
    constexpr int PAD = (KS - 1) / 2;
    constexpr int K2 = KS * KS;
    constexpr int PX = 2;
    constexpr int CO_S = (COUT + 3) & ~3;
    constexpr int WQ = CO_S / 4;
    __shared__ float sw[CIN * K2 * CO_S];

    const int W = 1 << lw;
    const int total = H << lw;
    const int idx = (blockIdx.x * THREADS + threadIdx.x) * PX;
    const float* ip0 = in + (size_t)blockIdx.y * bs_in;
    float* op = out + (size_t)blockIdx.y * bs_out;
    const int x0 = idx & (W - 1);               // even
    const int y  = idx >> lw;

    for (int i = threadIdx.x; i < CIN * K2 * COUT; i += THREADS) {
        const int co = i % COUT;
        const int rest = i / COUT;
        sw[rest * CO_S + co] = wt[i];
    }
    __syncthreads();

    float acc[COUT][PX];
#pragma unroll
    for (int co = 0; co < COUT; ++co) {
        const float b = bias[co];
#pragma unroll
        for (int j = 0; j < PX; ++j) acc[co][j] = b;
    }

#pragma unroll 1
    for (int cl = 0; cl < CIN; ++cl) {
        const float* __restrict__ row0 = ip0 + (size_t)cl * total;
        // ---- preload KS rows (float2-pair loads, pair-uniform validity) ----
        float r[KS][PX + KS - 1];
#pragma unroll
        for (int ky = 0; ky < KS; ++ky) {
            const int yy = y + ky - PAD;
            const bool vy = (unsigned)yy < (unsigned)H;
            const float* __restrict__ rp = row0 + (yy << lw);
            if (KS == 5) {
                float2 a = make_float2(0.f, 0.f), b = a, c = a;
                if (vy && x0 >= 2)    a = *reinterpret_cast<const float2*>(rp + x0 - 2);
                if (vy)               b = *reinterpret_cast<const float2*>(rp + x0);
                if (vy && x0 + 3 < W) c = *reinterpret_cast<const float2*>(rp + x0 + 2);
                r[ky][0] = a.x; r[ky][1] = a.y; r[ky][2] = b.x;
                r[ky][3] = b.y; r[ky][4] = c.x; r[ky][5] = c.y;
            } else {
                float2 b = make_float2(0.f, 0.f);
                if (vy) b = *reinterpret_cast<const float2*>(rp + x0);
                r[ky][1] = b.x; r[ky][2] = b.y;
                r[ky][0] = (vy && x0 >= 1)     ? rp[x0 - 1] : 0.f;
                r[ky][3] = (vy && x0 + 2 < W)  ? rp[x0 + 2] : 0.f;
            }
        }
        // ---- FMA sweep: fenced region per tap, direct b128 broadcasts ----
        const float* __restrict__ wbase = &sw[cl * K2 * CO_S];
#pragma unroll
        for (int t = 0; t < K2; ++t) {
            const int ky = t / KS, kx = t % KS;
            const float4* __restrict__ wv =
                reinterpret_cast<const float4*>(wbase + t * CO_S);
#pragma unroll
            for (int q = 0; q < WQ; ++q) {
                const float4 w = wv[q];
                const float wc[4] = {w.x, w.y, w.z, w.w};
#pragma unroll
                for (int c = 0; c < 4; ++c) {
                    const int co = 4 * q + c;
                    if (co < COUT) {
#pragma unroll
                        for (int j = 0; j < PX; ++j)
                            acc[co][j] = fmaf(r[ky][kx + j], wc[c], acc[co][j]);
                    }
                }
            }
            __builtin_amdgcn_sched_barrier(0);
        }
    }

#pragma unroll
    for (int co = 0; co < COUT; ++co) {
        float2 v;
        v.x = ACT ? silu_f(acc[co][0]) : acc[co][0];
        v.y = ACT ? silu_f(acc[co][1]) : acc[co][1];
        *reinterpret_cast<float2*>(op + (size_t)co * total + idx) = v;
    }
}

// ---------------------------------------------------------------------------
// DeformConv2d: 3x3, stride 1, pad 1, no bias. groups=2, offset groups=2.
// Per-group transposed weights [c][k][col] staged into LDS.
// offset layout: [OG=2][K=9][2(dy,dx)][H][W]
// ---------------------------------------------------------------------------
template<int CIN, int COUT>
__global__ __launch_bounds__(THREADS)
void dconv_k(const float* __restrict__ in, const float* __restrict__ off,
             const float* __restrict__ twg0, const float* __restrict__ twg1,
             float* __restrict__ out,
             int H, int lw, int bs_in, int bs_off, int bs_out)
{
    constexpr int K = 9;
    constexpr int OG = 2;
    constexpr int COG = CIN / OG;
    constexpr int COUTG = COUT / 2;
    constexpr int NWG = COG * K * COUTG;
    __shared__ float sw[2 * NWG];
    for (int i = threadIdx.x; i < 2 * NWG; i += THREADS)
        sw[i] = (i < NWG) ? twg0[i] : twg1[i - NWG];
    __syncthreads();

    const int W = 1 << lw;
    const int total = H << lw;
    const int idx = blockIdx.x * THREADS + threadIdx.x;
    const float* ip0 = in + (size_t)blockIdx.y * bs_in;
    const float* offp = off + (size_t)blockIdx.y * bs_off;
    float* op = out + (size_t)blockIdx.y * bs_out;
    const int x = idx & (W - 1);
    const int y = idx >> lw;

    float acc[COUT];
#pragma unroll
    for (int co = 0; co < COUT; ++co) acc[co] = 0.f;

#pragma unroll
    for (int og = 0; og < OG; ++og) {
#pragma unroll
        for (int k = 0; k < K; ++k) {
            const int ki = k / 3 - 1;
            const int kj = k % 3 - 1;
            const float dy = offp[(size_t)(((og * K + k) * 2 + 0)) * total + idx];
            const float dx = offp[(size_t)(((og * K + k) * 2 + 1)) * total + idx];
            const float py = dy + (float)(y + ki);
            const float px = dx + (float)(x + kj);
            const float y0f = floorf(py), x0f = floorf(px);
            const float ly = py - y0f, lx = px - x0f;
            const int y0 = (int)y0f, x0 = (int)x0f;
            const int y1 = y0 + 1, x1 = x0 + 1;
            const bool vy0 = (unsigned)y0 < (unsigned)H;
            const bool vy1 = (unsigned)y1 < (unsigned)H;
            const bool vx0 = (unsigned)x0 < (unsigned)W;
            const bool vx1 = (unsigned)x1 < (unsigned)W;
            const int cy0 = min(max(y0, 0), H - 1), cy1 = min(max(y1, 0), H - 1);
            const int cx0 = min(max(x0, 0), W - 1), cx1 = min(max(x1, 0), W - 1);
            const int i00 = (cy0 << lw) + cx0, i01 = (cy0 << lw) + cx1;
            const int i10 = (cy1 << lw) + cx0, i11 = (cy1 << lw) + cx1;
            const float f00 = (vy0 && vx0) ? (1.f - ly) * (1.f - lx) : 0.f;
            const float f01 = (vy0 && vx1) ? (1.f - ly) * lx : 0.f;
            const float f10 = (vy1 && vx0) ? ly * (1.f - lx) : 0.f;
            const float f11 = (vy1 && vx1) ? ly * lx : 0.f;
            const float* swg = &sw[og * NWG];
#pragma unroll
            for (int c = 0; c < COG; ++c) {
                const float* __restrict__ ip = ip0 + (size_t)(og * COG + c) * total;
                const float v = f00 * ip[i00] + f01 * ip[i01]
                              + f10 * ip[i10] + f11 * ip[i11];
                const float* __restrict__ wr = &swg[(c * K + k) * COUTG];
#pragma unroll
                for (int col = 0; col < COUTG; ++col)
                    acc[og * COUTG + col] = fmaf(v, wr[col], acc[og * COUTG + col]);
            }
        }
    }

#pragma unroll
    for (int co = 0; co < COUT; ++co)
        op[(size_t)co * total + idx] = acc[co];
}

// 2x2 average pool. n = C*Ho*Wo, lt = log2(Ho*Wo), lwo = log2(Wo).
__global__ __launch_bounds__(THREADS)
void avgpool_k(const float* __restrict__ in, float* __restrict__ out,
               int n, int lt, int lwo, int bsi, int bso)
{
    const int idx = blockIdx.x * THREADS + threadIdx.x;
    if (idx >= n) return;
    const float* ip0 = in + (size_t)blockIdx.y * bsi;
    float* op = out + (size_t)blockIdx.y * bso;
    const int c = idx >> lt;
    const int r = idx & ((1 << lt) - 1);
    const int oy = r >> lwo;
    const int ox = r & ((1 << lwo) - 1);
    const int Wi = 2 << lwo;
    const float* ip = ip0 + ((size_t)c << (lt + 2)) + ((size_t)(2 * oy) << (lwo + 1)) + 2 * ox;
    const float2 t = *reinterpret_cast<const float2*>(ip);
    const float2 b = *reinterpret_cast<const float2*>(ip + Wi);
    op[idx] = 0.25f * (t.x + t.y + b.x + b.y);
}

// Bilinear 2x upsample, align_corners=True.
__global__ __launch_bounds__(THREADS)
void up2x_k(const float* __restrict__ in, float* __restrict__ out,
            int n, int lt, int lwo, int Hin, int bsi, int bso)
{
    const int idx = blockIdx.x * THREADS + threadIdx.x;
    if (idx >= n) return;
    const float* ip0 = in + (size_t)blockIdx.y * bsi;
    float* op = out + (size_t)blockIdx.y * bso;
    const int c = idx >> lt;
    const int r = idx & ((1 << lt) - 1);
    const int oy = r >> lwo;
    const int ox = r & ((1 << lwo) - 1);
    const int W = 1 << (lwo - 1);
    const int H = Hin;
    const float s = (float)(H - 1) / (float)(2 * H - 1);
    const float fy = (float)oy * s;
    const float fx = (float)ox * s;
    const int y0 = (int)fy;
    const int x0 = (int)fx;
    const int y1 = min(y0 + 1, H - 1);
    const int x1 = min(x0 + 1, W - 1);
    const float wy = fy - (float)y0;
    const float wx = fx - (float)x0;
    const float* ip = ip0 + ((size_t)c << (lt - 2));
    const float v00 = ip[y0 * W + x0], v01 = ip[y0 * W + x1];
    const float v10 = ip[y1 * W + x0], v11 = ip[y1 * W + x1];
    op[idx] = (v00 * (1.f - wy) + v10 * wy) * (1.f - wx)
            + (v01 * (1.f - wy) + v11 * wy) * wx;
}

// strided batched d2d copy (float4 granularity)
__global__ __launch_bounds__(THREADS)
void copy_k(float4* __restrict__ dst, const float4* __restrict__ src,
            int n4, int bsd, int bss)
{
    const int i = blockIdx.x * THREADS + threadIdx.x;
    if (i >= n4) return;
    dst[(size_t)blockIdx.y * bsd + i] = src[(size_t)blockIdx.y * bss + i];
}

// ---------------------------------------------------------------------------

extern "C" void kernel_launch(void* const* d_in, const int* in_sizes, int n_in,
                              void* d_out, int out_size, void* d_ws, size_t ws_size,
                              hipStream_t stream) {
    const float* x      = (const float*)d_in[0];
    const float* eo1_b1 = (const float*)d_in[2];
    const float* eo1_b2 = (const float*)d_in[4];
    const float* c1d_b1 = (const float*)d_in[7];
    const float* c1d_b2 = (const float*)d_in[9];
    const float* eo2_b1 = (const float*)d_in[11];
    const float* eo2_b2 = (const float*)d_in[13];
    const float* c2d_b1 = (const float*)d_in[16];
    const float* c2d_b2 = (const float*)d_in[18];
    const float* eo3_b1 = (const float*)d_in[20];
    const float* eo3_b2 = (const float*)d_in[22];
    const float* c3d_b1 = (const float*)d_in[25];
    const float* c3d_b2 = (const float*)d_in[27];
    const float* up2_b  = (const float*)d_in[29];
    const float* c2u_b1 = (const float*)d_in[31];
    const float* c2u_b2 = (const float*)d_in[33];
    const float* up1_b  = (const float*)d_in[35];
    const float* c1u_b1 = (const float*)d_in[37];
    const float* c1u_b2 = (const float*)d_in[39];

    float* out = (float*)d_out;
    float* wsf = (float*)d_ws;

    constexpr int H1 = 512, A1 = H1 * H1;
    constexpr int H2 = 256, A2 = H2 * H2;
    constexpr int H3 = 128, A3 = H3 * H3;
    constexpr int TW_FLOATS = 81920;
    constexpr int SLOT = 70 * A1 + 24 * A2;

    // ---- transposed-weight table: 21 conv entries (36-out convs split into
    //      two 18-out halves) + 6 dconv group entries ----
    const int widx[21]  = {1, 3, 3, 6, 8, 10, 12, 12, 15, 17, 19, 21, 21, 24, 26, 28, 30, 32, 34, 36, 38};
    const int wcin[21]  = {4, 18, 18, 2, 4, 8, 18, 18, 8, 12, 16, 18, 18, 16, 14, 12, 28, 16, 8, 16, 8};
    const int wcout[21] = {18, 18, 18, 4, 8, 18, 18, 18, 12, 16, 18, 18, 18, 14, 12, 12, 16, 8, 8, 8, 2};
    const int wk2[21]   = {25, 25, 25, 9, 9, 25, 25, 25, 9, 9, 25, 25, 25, 9, 9, 9, 9, 9, 9, 9, 9};
    const int wsoff[21] = {0, 0, 8100, 0, 0, 0, 0, 8100, 0, 0, 0, 0, 8100, 0, 0, 0, 0, 0, 0, 0, 0};
    TTab tab;
    const float* tw[27];
    int off = 0, base = 0;
    for (int i = 0; i < 21; ++i) {
        const int n = wcin[i] * wcout[i] * wk2[i];
        tab.e[i].src = (const float*)d_in[widx[i]] + wsoff[i];
        tab.e[i].dst = off; tab.e[i].cin = wcin[i]; tab.e[i].cout = wcout[i];
        tab.e[i].k2 = wk2[i]; tab.e[i].base = base; tab.e[i].n = n;
        tw[i] = wsf + off;
        off = (off + n + 63) & ~63;
        base += n;
    }
    const int didx[3]   = {5, 14, 23};
    const int dcoutg[3] = {1, 4, 8};
    const int dcpg[3]   = {2, 4, 8};
    for (int i = 0; i < 3; ++i) {
        for (int g = 0; g < 2; ++g) {
            const int e = 21 + 2 * i + g;
            const int n = dcoutg[i] * dcpg[i] * 9;
            tab.e[e].src = (const float*)d_in[didx[i]] + (size_t)g * n;
            tab.e[e].dst = off; tab.e[e].cin = dcpg[i]; tab.e[e].cout = dcoutg[i];
            tab.e[e].k2 = 9; tab.e[e].base = base; tab.e[e].n = n;
            tw[e] = wsf + off;
            off = (off + n + 63) & ~63;
            base += n;
        }
    }
    tab.total = base;
    transpose_w_k<<<(base + THREADS - 1) / THREADS, THREADS, 0, stream>>>(tab, wsf);

    int B = 4;
    while (B > 1 && ws_size < ((size_t)TW_FLOATS + (size_t)B * SLOT) * sizeof(float)) B >>= 1;

    auto run_all = [&](int Bc, float* slot, int SB,
                       const float* xin, int xbs, float* outp, int obs) {
        float* S0 = slot;                // 36*A1
        float* S1 = S0 + 36 * A1;        // 18*A1
        float* S2 = S1 + 18 * A1;        //  8*A1
        float* P  = S2 + 8 * A1;         //  8*A2
        float* L1 = P + 8 * A2;          //  8*A1  (conv1_d skip)
        float* L2 = L1 + 8 * A1;         // 16*A2  (conv2_d skip)
        auto g2 = [&](int n) { return dim3(n / (2 * THREADS), Bc); };
        auto g1 = [&](int n) { return dim3((n + THREADS - 1) / THREADS, Bc); };

        // ---- level 1 down ----
        conv_k<4, 18, 5, false><<<g2(A1), THREADS, 0, stream>>>(xin, tw[0], eo1_b1, S1, H1, 9, xbs, SB);
        conv_k<18, 18, 5, false><<<g2(A1), THREADS, 0, stream>>>(S1, tw[1], eo1_b2, S0, H1, 9, SB, SB);
        conv_k<18, 18, 5, false><<<g2(A1), THREADS, 0, stream>>>(S1, tw[2], eo1_b2 + 18, S0 + 18 * A1, H1, 9, SB, SB);
        dconv_k<4, 2><<<g1(A1), THREADS, 0, stream>>>(xin, S0, tw[21], tw[22], S2, H1, 9, xbs, SB, SB);
        conv_k<2, 4, 3, true><<<g2(A1), THREADS, 0, stream>>>(S2, tw[3], c1d_b1, S1, H1, 9, SB, SB);
        conv_k<4, 8, 3, true><<<g2(A1), THREADS, 0, stream>>>(S1, tw[4], c1d_b2, L1, H1, 9, SB, SB);
        avgpool_k<<<g1(8 * A2), THREADS, 0, stream>>>(L1, P, 8 * A2, 16, 8, SB, SB);

        // ---- level 2 down ----
        conv_k<8, 18, 5, false><<<g2(A2), THREADS, 0, stream>>>(P, tw[5], eo2_b1, S1, H2, 8, SB, SB);
        conv_k<18, 18, 5, false><<<g2(A2), THREADS, 0, stream>>>(S1, tw[6], eo2_b2, S0, H2, 8, SB, SB);
        conv_k<18, 18, 5, false><<<g2(A2), THREADS, 0, stream>>>(S1, tw[7], eo2_b2 + 18, S0 + 18 * A2, H2, 8, SB, SB);
        dconv_k<8, 8><<<g1(A2), THREADS, 0, stream>>>(P, S0, tw[23], tw[24], S2, H2, 8, SB, SB, SB);
        conv_k<8, 12, 3, true><<<g2(A2), THREADS, 0, stream>>>(S2, tw[8], c2d_b1, S1, H2, 8, SB, SB);
        conv_k<12, 16, 3, true><<<g2(A2), THREADS, 0, stream>>>(S1, tw[9], c2d_b2, L2, H2, 8, SB, SB);
        avgpool_k<<<g1(16 * A3), THREADS, 0, stream>>>(L2, P, 16 * A3, 14, 7, SB, SB);

        // ---- level 3 (bottleneck) ----
        conv_k<16, 18, 5, false><<<g2(A3), THREADS, 0, stream>>>(P, tw[10], eo3_b1, S1, H3, 7, SB, SB);
        conv_k<18, 18, 5, false><<<g2(A3), THREADS, 0, stream>>>(S1, tw[11], eo3_b2, S0, H3, 7, SB, SB);
        conv_k<18, 18, 5, false><<<g2(A3), THREADS, 0, stream>>>(S1, tw[12], eo3_b2 + 18, S0 + 18 * A3, H3, 7, SB, SB);
        dconv_k<16, 16><<<g1(A3), THREADS, 0, stream>>>(P, S0, tw[25], tw[26], S2, H3, 7, SB, SB, SB);
        conv_k<16, 14, 3, true><<<g2(A3), THREADS, 0, stream>>>(S2, tw[13], c3d_b1, S1, H3, 7, SB, SB);
        conv_k<14, 12, 3, true><<<g2(A3), THREADS, 0, stream>>>(S1, tw[14], c3d_b2, S2, H3, 7, SB, SB);

        // ---- up path level 2 ----
        up2x_k<<<g1(12 * A2), THREADS, 0, stream>>>(S2, S0, 12 * A2, 16, 8, H3, SB, SB);
        conv_k<12, 12, 3, true><<<g2(A2), THREADS, 0, stream>>>(S0, tw[15], up2_b, S1, H2, 8, SB, SB);
        copy_k<<<g1(4 * A2), THREADS, 0, stream>>>((float4*)(S1 + 12 * A2), (const float4*)L2,
                                                   4 * A2, SB / 4, SB / 4);
        conv_k<28, 16, 3, true><<<g2(A2), THREADS, 0, stream>>>(S1, tw[16], c2u_b1, S0, H2, 8, SB, SB);
        conv_k<16, 8, 3, true><<<g2(A2), THREADS, 0, stream>>>(S0, tw[17], c2u_b2, S2, H2, 8, SB, SB);

        // ---- up path level 1 ----
        up2x_k<<<g1(8 * A1), THREADS, 0, stream>>>(S2, S0, 8 * A1, 18, 9, H2, SB, SB);
        conv_k<8, 8, 3, true><<<g2(A1), THREADS, 0, stream>>>(S0, tw[18], up1_b, S1, H1, 9, SB, SB);
        copy_k<<<g1(2 * A1), THREADS, 0, stream>>>((float4*)(S1 + 8 * A1), (const float4*)L1,
                                                   2 * A1, SB / 4, SB / 4);
        conv_k<16, 8, 3, true><<<g2(A1), THREADS, 0, stream>>>(S1, tw[19], c1u_b1, S0, H1, 9, SB, SB);
        conv_k<8, 2, 3, true><<<g2(A1), THREADS, 0, stream>>>(S0, tw[20], c1u_b2, outp, H1, 9, SB, obs);
    };

    for (int g = 0; g < 4; g += B)
        run_all(B, wsf + TW_FLOATS, SLOT,
                x + (size_t)g * 4 * A1, 4 * A1,
                out + (size_t)g * 2 * A1, 2 * A1);
}

// Round 8
// 2001.762 us; speedup vs baseline: 1.3766x; 1.0209x over previous
//
#include <hip/hip_runtime.h>
#include <math.h>

#define THREADS 256

__device__ __forceinline__ float silu_f(float v) {
    return v / (1.f + __expf(-v));
}

// ---------------------------------------------------------------------------
// Weight transpose: [co][ci][k2] -> [ci][k2][co]  (co contiguous)
// Used per-slice (12-out / 18-out) for convs and per-group for deform-conv.
// ---------------------------------------------------------------------------
struct TEnt { const float* src; int dst; int cin; int cout; int k2; int base; int n; };
struct TTab { TEnt e[32]; int total; };

__global__ __launch_bounds__(THREADS)
void transpose_w_k(TTab t, float* __restrict__ tw) {
    const int i = blockIdx.x * THREADS + threadIdx.x;
    if (i >= t.total) return;
    int j = 0;
    while (i >= t.e[j].base + t.e[j].n) ++j;
    const TEnt e = t.e[j];
    const int local = i - e.base;
    const int co  = local % e.cout;
    const int tmp = local / e.cout;
    const int k   = tmp % e.k2;
    const int ci  = tmp / e.k2;
    tw[e.dst + local] = e.src[(co * e.cin + ci) * e.k2 + k];
}

// ---------------------------------------------------------------------------
// Direct conv2d, stride 1, pad (KS-1)/2, NCHW. PX pixels per thread (x0
// multiple of PX), all COUT channels in registers. Weights in LDS,
// CO_S-padded -> b128 broadcast reads. ds:VALU balance needs 4co*PX >= 24,
// hence COUT<=12 slices with PX=8 at 512^2 (round-7 analysis: the per-CU
// LDS pipe is shared by 4 SIMDs; ds traffic is PX-independent).
// Per-tap sched_barrier(0) pins live ranges (round-4 spill lesson);
// 2-stage weight prefetch only when WQ<=3 (+24 VGPR max).
// ---------------------------------------------------------------------------
template<int CIN, int COUT, int KS, bool ACT, int PX>
__global__ __launch_bounds__(THREADS)
void conv_k(const float* __restrict__ in, const float* __restrict__ wt,
            const float* __restrict__ bias, float* __restrict__ out,
            int H, int lw, int bs_in, int bs_out)
{
    constexpr int PAD = (KS - 1) / 2;
    constexpr int K2 = KS * KS;
    constexpr int CO_S = (COUT + 3) & ~3;
    constexpr int WQ = CO_S / 4;
    constexpr int RW = PX + KS - 1;
    __shared__ float sw[CIN * K2 * CO_S];

    const int W = 1 << lw;
    const int total = H << lw;
    const int idx = (blockIdx.x * THREADS + threadIdx.x) * PX;
    const float* ip0 = in + (size_t)blockIdx.y * bs_in;
    float* op = out + (size_t)blockIdx.y * bs_out;
    const int x0 = idx & (W - 1);               // multiple of PX
    const int y  = idx >> lw;

    for (int i = threadIdx.x; i < CIN * K2 * COUT; i += THREADS) {
        const int co = i % COUT;
        const int rest = i / COUT;
        sw[rest * CO_S + co] = wt[i];
    }
    __syncthreads();

    float acc[COUT][PX];
#pragma unroll
    for (int co = 0; co < COUT; ++co) {
        const float b = bias[co];
#pragma unroll
        for (int j = 0; j < PX; ++j) acc[co][j] = b;
    }

#pragma unroll 1
    for (int cl = 0; cl < CIN; ++cl) {
        const float* __restrict__ row0 = ip0 + (size_t)cl * total;
        // ---- preload KS rows via aligned float4 chunks; per-element
        //      boundary fallback (edges only) ----
        float r[KS][RW];
#pragma unroll
        for (int ky = 0; ky < KS; ++ky) {
            const int yy = y + ky - PAD;
            const bool vy = (unsigned)yy < (unsigned)H;
            const float* __restrict__ rp = row0 + (yy << lw);
#pragma unroll
            for (int q = -1; q <= PX / 4; ++q) {
                if (4 * q + 3 + PAD < 0 || 4 * q + PAD >= RW) continue;
                const int xs = x0 + 4 * q;
                float vc[4] = {0.f, 0.f, 0.f, 0.f};
                if (vy && xs >= 0 && xs + 4 <= W) {
                    const float4 v = *reinterpret_cast<const float4*>(rp + xs);
                    vc[0] = v.x; vc[1] = v.y; vc[2] = v.z; vc[3] = v.w;
                } else if (vy) {
#pragma unroll
                    for (int c = 0; c < 4; ++c)
                        vc[c] = ((unsigned)(xs + c) < (unsigned)W) ? rp[xs + c] : 0.f;
                }
#pragma unroll
                for (int c = 0; c < 4; ++c) {
                    const int t = 4 * q + c + PAD;
                    if (t >= 0 && t < RW) r[ky][t] = vc[c];
                }
            }
        }
        // ---- FMA sweep over K2 taps ----
        const float* __restrict__ wbase = &sw[cl * K2 * CO_S];
        if constexpr (WQ <= 3) {
            float4 wb[2][WQ];
#pragma unroll
            for (int q = 0; q < WQ; ++q)
                wb[0][q] = reinterpret_cast<const float4*>(wbase)[q];
#pragma unroll
            for (int t = 0; t < K2; ++t) {
                const int cur = t & 1;
                if (t + 1 < K2) {
                    const float4* __restrict__ nx =
                        reinterpret_cast<const float4*>(wbase + (t + 1) * CO_S);
#pragma unroll
                    for (int q = 0; q < WQ; ++q) wb[cur ^ 1][q] = nx[q];
                }
                const int ky = t / KS, kx = t % KS;
#pragma unroll
                for (int q = 0; q < WQ; ++q) {
                    const float4 w = wb[cur][q];
                    const float wc[4] = {w.x, w.y, w.z, w.w};
#pragma unroll
                    for (int c = 0; c < 4; ++c) {
                        const int co = 4 * q + c;
                        if (co < COUT) {
#pragma unroll
                            for (int j = 0; j < PX; ++j)
                                acc[co][j] = fmaf(r[ky][kx + j], wc[c], acc[co][j]);
                        }
                    }
                }
                __builtin_amdgcn_sched_barrier(0);
            }
        } else {
#pragma unroll
            for (int t = 0; t < K2; ++t) {
                const int ky = t / KS, kx = t % KS;
                const float4* __restrict__ wv =
                    reinterpret_cast<const float4*>(wbase + t * CO_S);
#pragma unroll
                for (int q = 0; q < WQ; ++q) {
                    const float4 w = wv[q];
                    const float wc[4] = {w.x, w.y, w.z, w.w};
#pragma unroll
                    for (int c = 0; c < 4; ++c) {
                        const int co = 4 * q + c;
                        if (co < COUT) {
#pragma unroll
                            for (int j = 0; j < PX; ++j)
                                acc[co][j] = fmaf(r[ky][kx + j], wc[c], acc[co][j]);
                        }
                    }
                }
                __builtin_amdgcn_sched_barrier(0);
            }
        }
    }

#pragma unroll
    for (int co = 0; co < COUT; ++co) {
        if (PX == 2) {
            float2 v;
            v.x = ACT ? silu_f(acc[co][0]) : acc[co][0];
            v.y = ACT ? silu_f(acc[co][1]) : acc[co][1];
            *reinterpret_cast<float2*>(op + (size_t)co * total + idx) = v;
        } else {
#pragma unroll
            for (int j4 = 0; j4 < PX / 4; ++j4) {
                float4 v;
                v.x = ACT ? silu_f(acc[co][4 * j4 + 0]) : acc[co][4 * j4 + 0];
                v.y = ACT ? silu_f(acc[co][4 * j4 + 1]) : acc[co][4 * j4 + 1];
                v.z = ACT ? silu_f(acc[co][4 * j4 + 2]) : acc[co][4 * j4 + 2];
                v.w = ACT ? silu_f(acc[co][4 * j4 + 3]) : acc[co][4 * j4 + 3];
                *reinterpret_cast<float4*>(op + (size_t)co * total + idx + 4 * j4) = v;
            }
        }
    }
}

// ---------------------------------------------------------------------------
// DeformConv2d: 3x3, stride 1, pad 1, no bias. groups=2, offset groups=2.
// ---------------------------------------------------------------------------
template<int CIN, int COUT>
__global__ __launch_bounds__(THREADS)
void dconv_k(const float* __restrict__ in, const float* __restrict__ off,
             const float* __restrict__ twg0, const float* __restrict__ twg1,
             float* __restrict__ out,
             int H, int lw, int bs_in, int bs_off, int bs_out)
{
    constexpr int K = 9;
    constexpr int OG = 2;
    constexpr int COG = CIN / OG;
    constexpr int COUTG = COUT / 2;
    constexpr int NWG = COG * K * COUTG;
    __shared__ float sw[2 * NWG];
    for (int i = threadIdx.x; i < 2 * NWG; i += THREADS)
        sw[i] = (i < NWG) ? twg0[i] : twg1[i - NWG];
    __syncthreads();

    const int W = 1 << lw;
    const int total = H << lw;
    const int idx = blockIdx.x * THREADS + threadIdx.x;
    const float* ip0 = in + (size_t)blockIdx.y * bs_in;
    const float* offp = off + (size_t)blockIdx.y * bs_off;
    float* op = out + (size_t)blockIdx.y * bs_out;
    const int x = idx & (W - 1);
    const int y = idx >> lw;

    float acc[COUT];
#pragma unroll
    for (int co = 0; co < COUT; ++co) acc[co] = 0.f;

#pragma unroll
    for (int og = 0; og < OG; ++og) {
#pragma unroll
        for (int k = 0; k < K; ++k) {
            const int ki = k / 3 - 1;
            const int kj = k % 3 - 1;
            const float dy = offp[(size_t)(((og * K + k) * 2 + 0)) * total + idx];
            const float dx = offp[(size_t)(((og * K + k) * 2 + 1)) * total + idx];
            const float py = dy + (float)(y + ki);
            const float px = dx + (float)(x + kj);
            const float y0f = floorf(py), x0f = floorf(px);
            const float ly = py - y0f, lx = px - x0f;
            const int y0 = (int)y0f, x0 = (int)x0f;
            const int y1 = y0 + 1, x1 = x0 + 1;
            const bool vy0 = (unsigned)y0 < (unsigned)H;
            const bool vy1 = (unsigned)y1 < (unsigned)H;
            const bool vx0 = (unsigned)x0 < (unsigned)W;
            const bool vx1 = (unsigned)x1 < (unsigned)W;
            const int cy0 = min(max(y0, 0), H - 1), cy1 = min(max(y1, 0), H - 1);
            const int cx0 = min(max(x0, 0), W - 1), cx1 = min(max(x1, 0), W - 1);
            const int i00 = (cy0 << lw) + cx0, i01 = (cy0 << lw) + cx1;
            const int i10 = (cy1 << lw) + cx0, i11 = (cy1 << lw) + cx1;
            const float f00 = (vy0 && vx0) ? (1.f - ly) * (1.f - lx) : 0.f;
            const float f01 = (vy0 && vx1) ? (1.f - ly) * lx : 0.f;
            const float f10 = (vy1 && vx0) ? ly * (1.f - lx) : 0.f;
            const float f11 = (vy1 && vx1) ? ly * lx : 0.f;
            const float* swg = &sw[og * NWG];
#pragma unroll
            for (int c = 0; c < COG; ++c) {
                const float* __restrict__ ip = ip0 + (size_t)(og * COG + c) * total;
                const float v = f00 * ip[i00] + f01 * ip[i01]
                              + f10 * ip[i10] + f11 * ip[i11];
                const float* __restrict__ wr = &swg[(c * K + k) * COUTG];
#pragma unroll
                for (int col = 0; col < COUTG; ++col)
                    acc[og * COUTG + col] = fmaf(v, wr[col], acc[og * COUTG + col]);
            }
        }
    }

#pragma unroll
    for (int co = 0; co < COUT; ++co)
        op[(size_t)co * total + idx] = acc[co];
}

// 2x2 average pool. n = C*Ho*Wo, lt = log2(Ho*Wo), lwo = log2(Wo).
__global__ __launch_bounds__(THREADS)
void avgpool_k(const float* __restrict__ in, float* __restrict__ out,
               int n, int lt, int lwo, int bsi, int bso)
{
    const int idx = blockIdx.x * THREADS + threadIdx.x;
    if (idx >= n) return;
    const float* ip0 = in + (size_t)blockIdx.y * bsi;
    float* op = out + (size_t)blockIdx.y * bso;
    const int c = idx >> lt;
    const int r = idx & ((1 << lt) - 1);
    const int oy = r >> lwo;
    const int ox = r & ((1 << lwo) - 1);
    const int Wi = 2 << lwo;
    const float* ip = ip0 + ((size_t)c << (lt + 2)) + ((size_t)(2 * oy) << (lwo + 1)) + 2 * ox;
    const float2 t = *reinterpret_cast<const float2*>(ip);
    const float2 b = *reinterpret_cast<const float2*>(ip + Wi);
    op[idx] = 0.25f * (t.x + t.y + b.x + b.y);
}

// Bilinear 2x upsample, align_corners=True.
__global__ __launch_bounds__(THREADS)
void up2x_k(const float* __restrict__ in, float* __restrict__ out,
            int n, int lt, int lwo, int Hin, int bsi, int bso)
{
    const int idx = blockIdx.x * THREADS + threadIdx.x;
    if (idx >= n) return;
    const float* ip0 = in + (size_t)blockIdx.y * bsi;
    float* op = out + (size_t)blockIdx.y * bso;
    const int c = idx >> lt;
    const int r = idx & ((1 << lt) - 1);
    const int oy = r >> lwo;
    const int ox = r & ((1 << lwo) - 1);
    const int W = 1 << (lwo - 1);
    const int H = Hin;
    const float s = (float)(H - 1) / (float)(2 * H - 1);
    const float fy = (float)oy * s;
    const float fx = (float)ox * s;
    const int y0 = (int)fy;
    const int x0 = (int)fx;
    const int y1 = min(y0 + 1, H - 1);
    const int x1 = min(x0 + 1, W - 1);
    const float wy = fy - (float)y0;
    const float wx = fx - (float)x0;
    const float* ip = ip0 + ((size_t)c << (lt - 2));
    const float v00 = ip[y0 * W + x0], v01 = ip[y0 * W + x1];
    const float v10 = ip[y1 * W + x0], v11 = ip[y1 * W + x1];
    op[idx] = (v00 * (1.f - wy) + v10 * wy) * (1.f - wx)
            + (v01 * (1.f - wy) + v11 * wy) * wx;
}

// strided batched d2d copy (float4 granularity)
__global__ __launch_bounds__(THREADS)
void copy_k(float4* __restrict__ dst, const float4* __restrict__ src,
            int n4, int bsd, int bss)
{
    const int i = blockIdx.x * THREADS + threadIdx.x;
    if (i >= n4) return;
    dst[(size_t)blockIdx.y * bsd + i] = src[(size_t)blockIdx.y * bss + i];
}

// ---------------------------------------------------------------------------

extern "C" void kernel_launch(void* const* d_in, const int* in_sizes, int n_in,
                              void* d_out, int out_size, void* d_ws, size_t ws_size,
                              hipStream_t stream) {
    const float* x      = (const float*)d_in[0];
    const float* eo1_b1 = (const float*)d_in[2];
    const float* eo1_b2 = (const float*)d_in[4];
    const float* c1d_b1 = (const float*)d_in[7];
    const float* c1d_b2 = (const float*)d_in[9];
    const float* eo2_b1 = (const float*)d_in[11];
    const float* eo2_b2 = (const float*)d_in[13];
    const float* c2d_b1 = (const float*)d_in[16];
    const float* c2d_b2 = (const float*)d_in[18];
    const float* eo3_b1 = (const float*)d_in[20];
    const float* eo3_b2 = (const float*)d_in[22];
    const float* c3d_b1 = (const float*)d_in[25];
    const float* c3d_b2 = (const float*)d_in[27];
    const float* up2_b  = (const float*)d_in[29];
    const float* c2u_b1 = (const float*)d_in[31];
    const float* c2u_b2 = (const float*)d_in[33];
    const float* up1_b  = (const float*)d_in[35];
    const float* c1u_b1 = (const float*)d_in[37];
    const float* c1u_b2 = (const float*)d_in[39];

    float* out = (float*)d_out;
    float* wsf = (float*)d_ws;

    constexpr int H1 = 512, A1 = H1 * H1;
    constexpr int H2 = 256, A2 = H2 * H2;
    constexpr int H3 = 128, A3 = H3 * H3;
    constexpr int TW_FLOATS = 81920;
    constexpr int SLOT = 58 * A1;   // slimmed: L1/L2 folded into S1/S0 tails

    // ---- transposed-weight table: 23 conv entries + 6 dconv groups ----
    const int widx[23] = {1, 3, 3, 3, 6, 8, 10, 12, 12, 12, 19, 21, 21,
                          15, 17, 24, 26, 28, 30, 32, 34, 36, 38};
    const int wcin[23] = {4, 18, 18, 18, 2, 4, 8, 18, 18, 18, 16, 18, 18,
                          8, 12, 16, 14, 12, 28, 16, 8, 16, 8};
    const int wcout[23] = {18, 12, 12, 12, 4, 8, 18, 12, 12, 12, 18, 18, 18,
                           12, 16, 14, 12, 12, 16, 8, 8, 8, 2};
    const int wk2[23]  = {25, 25, 25, 25, 9, 9, 25, 25, 25, 25, 25, 25, 25,
                          9, 9, 9, 9, 9, 9, 9, 9, 9, 9};
    const int wsoff[23] = {0, 0, 5400, 10800, 0, 0, 0, 0, 5400, 10800, 0, 0, 8100,
                           0, 0, 0, 0, 0, 0, 0, 0, 0, 0};
    TTab tab;
    const float* tw[29];
    int off = 0, base = 0;
    for (int i = 0; i < 23; ++i) {
        const int n = wcin[i] * wcout[i] * wk2[i];
        tab.e[i].src = (const float*)d_in[widx[i]] + wsoff[i];
        tab.e[i].dst = off; tab.e[i].cin = wcin[i]; tab.e[i].cout = wcout[i];
        tab.e[i].k2 = wk2[i]; tab.e[i].base = base; tab.e[i].n = n;
        tw[i] = wsf + off;
        off = (off + n + 63) & ~63;
        base += n;
    }
    const int didx[3]   = {5, 14, 23};
    const int dcoutg[3] = {1, 4, 8};
    const int dcpg[3]   = {2, 4, 8};
    for (int i = 0; i < 3; ++i) {
        for (int g = 0; g < 2; ++g) {
            const int e = 23 + 2 * i + g;
            const int n = dcoutg[i] * dcpg[i] * 9;
            tab.e[e].src = (const float*)d_in[didx[i]] + (size_t)g * n;
            tab.e[e].dst = off; tab.e[e].cin = dcpg[i]; tab.e[e].cout = dcoutg[i];
            tab.e[e].k2 = 9; tab.e[e].base = base; tab.e[e].n = n;
            tw[e] = wsf + off;
            off = (off + n + 63) & ~63;
            base += n;
        }
    }
    tab.total = base;
    transpose_w_k<<<(base + THREADS - 1) / THREADS, THREADS, 0, stream>>>(tab, wsf);

    int B = 4;
    while (B > 1 && ws_size < ((size_t)TW_FLOATS + (size_t)B * SLOT) * sizeof(float)) B >>= 1;

    auto run_all = [&](int Bc, float* slot, int SB,
                       const float* xin, int xbs, float* outp, int obs) {
        float* S0 = slot;                // 36*A1 (off1/off2/off3, up2x/up1x, cat1)
        float* S1 = S0 + 36 * A1;        // 18*A1 (eo mids, conv mids, cat2)
        float* S2 = S1 + 18 * A1;        //  2*A1 (dconv outs, small mids)
        float* P  = S2 + 2 * A1;         //  2*A1 (pool outs)
        float* L1 = S1 + 10 * A1;        //  8*A1 tail of S1 (conv1_d skip)
        float* L2 = S0 + 32 * A1;        //  4*A1 tail of S0 (conv2_d skip)
        auto gp = [&](int n, int px) { return dim3(n / (px * THREADS), Bc); };
        auto g1 = [&](int n) { return dim3((n + THREADS - 1) / THREADS, Bc); };

        // ---- level 1 down ----
        conv_k<4, 18, 5, false, 4><<<gp(A1, 4), THREADS, 0, stream>>>(xin, tw[0], eo1_b1, S1, H1, 9, xbs, SB);
        conv_k<18, 12, 5, false, 8><<<gp(A1, 8), THREADS, 0, stream>>>(S1, tw[1], eo1_b2, S0, H1, 9, SB, SB);
        conv_k<18, 12, 5, false, 8><<<gp(A1, 8), THREADS, 0, stream>>>(S1, tw[2], eo1_b2 + 12, S0 + 12 * A1, H1, 9, SB, SB);
        conv_k<18, 12, 5, false, 8><<<gp(A1, 8), THREADS, 0, stream>>>(S1, tw[3], eo1_b2 + 24, S0 + 24 * A1, H1, 9, SB, SB);
        dconv_k<4, 2><<<g1(A1), THREADS, 0, stream>>>(xin, S0, tw[23], tw[24], S2, H1, 9, xbs, SB, SB);
        conv_k<2, 4, 3, true, 4><<<gp(A1, 4), THREADS, 0, stream>>>(S2, tw[4], c1d_b1, S1, H1, 9, SB, SB);
        conv_k<4, 8, 3, true, 4><<<gp(A1, 4), THREADS, 0, stream>>>(S1, tw[5], c1d_b2, L1, H1, 9, SB, SB);
        avgpool_k<<<g1(8 * A2), THREADS, 0, stream>>>(L1, P, 8 * A2, 16, 8, SB, SB);

        // ---- level 2 down ----
        conv_k<8, 18, 5, false, 2><<<gp(A2, 2), THREADS, 0, stream>>>(P, tw[6], eo2_b1, S1, H2, 8, SB, SB);
        conv_k<18, 12, 5, false, 4><<<gp(A2, 4), THREADS, 0, stream>>>(S1, tw[7], eo2_b2, S0, H2, 8, SB, SB);
        conv_k<18, 12, 5, false, 4><<<gp(A2, 4), THREADS, 0, stream>>>(S1, tw[8], eo2_b2 + 12, S0 + 12 * A2, H2, 8, SB, SB);
        conv_k<18, 12, 5, false, 4><<<gp(A2, 4), THREADS, 0, stream>>>(S1, tw[9], eo2_b2 + 24, S0 + 24 * A2, H2, 8, SB, SB);
        dconv_k<8, 8><<<g1(A2), THREADS, 0, stream>>>(P, S0, tw[25], tw[26], S2, H2, 8, SB, SB, SB);
        conv_k<8, 12, 3, true, 2><<<gp(A2, 2), THREADS, 0, stream>>>(S2, tw[13], c2d_b1, S1, H2, 8, SB, SB);
        conv_k<12, 16, 3, true, 2><<<gp(A2, 2), THREADS, 0, stream>>>(S1, tw[14], c2d_b2, L2, H2, 8, SB, SB);
        avgpool_k<<<g1(16 * A3), THREADS, 0, stream>>>(L2, P, 16 * A3, 14, 7, SB, SB);

        // ---- level 3 (bottleneck) ----
        conv_k<16, 18, 5, false, 2><<<gp(A3, 2), THREADS, 0, stream>>>(P, tw[10], eo3_b1, S1, H3, 7, SB, SB);
        conv_k<18, 18, 5, false, 2><<<gp(A3, 2), THREADS, 0, stream>>>(S1, tw[11], eo3_b2, S0, H3, 7, SB, SB);
        conv_k<18, 18, 5, false, 2><<<gp(A3, 2), THREADS, 0, stream>>>(S1, tw[12], eo3_b2 + 18, S0 + 18 * A3, H3, 7, SB, SB);
        dconv_k<16, 16><<<g1(A3), THREADS, 0, stream>>>(P, S0, tw[27], tw[28], S2, H3, 7, SB, SB, SB);
        conv_k<16, 14, 3, true, 2><<<gp(A3, 2), THREADS, 0, stream>>>(S2, tw[15], c3d_b1, S1, H3, 7, SB, SB);
        conv_k<14, 12, 3, true, 2><<<gp(A3, 2), THREADS, 0, stream>>>(S1, tw[16], c3d_b2, S2, H3, 7, SB, SB);

        // ---- up path level 2 ----
        up2x_k<<<g1(12 * A2), THREADS, 0, stream>>>(S2, S0, 12 * A2, 16, 8, H3, SB, SB);
        conv_k<12, 12, 3, true, 2><<<gp(A2, 2), THREADS, 0, stream>>>(S0, tw[17], up2_b, S1, H2, 8, SB, SB);
        copy_k<<<g1(4 * A2), THREADS, 0, stream>>>((float4*)(S1 + 12 * A2), (const float4*)L2,
                                                   4 * A2, SB / 4, SB / 4);
        conv_k<28, 16, 3, true, 2><<<gp(A2, 2), THREADS, 0, stream>>>(S1, tw[18], c2u_b1, S0, H2, 8, SB, SB);
        conv_k<16, 8, 3, true, 2><<<gp(A2, 2), THREADS, 0, stream>>>(S0, tw[19], c2u_b2, S2, H2, 8, SB, SB);

        // ---- up path level 1 ----
        up2x_k<<<g1(8 * A1), THREADS, 0, stream>>>(S2, S0, 8 * A1, 18, 9, H2, SB, SB);
        conv_k<8, 8, 3, true, 4><<<gp(A1, 4), THREADS, 0, stream>>>(S0, tw[20], up1_b, S0 + 8 * A1, H1, 9, SB, SB);
        copy_k<<<g1(2 * A1), THREADS, 0, stream>>>((float4*)(S0 + 16 * A1), (const float4*)L1,
                                                   2 * A1, SB / 4, SB / 4);
        conv_k<16, 8, 3, true, 4><<<gp(A1, 4), THREADS, 0, stream>>>(S0 + 8 * A1, tw[21], c1u_b1, S1, H1, 9, SB, SB);
        conv_k<8, 2, 3, true, 4><<<gp(A1, 4), THREADS, 0, stream>>>(S1, tw[22], c1u_b2, outp, H1, 9, SB, obs);
    };

    for (int g = 0; g < 4; g += B)
        run_all(B, wsf + TW_FLOATS, SLOT,
                x + (size_t)g * 4 * A1, 4 * A1,
                out + (size_t)g * 2 * A1, 2 * A1);
}

// Round 9
// 1991.849 us; speedup vs baseline: 1.3834x; 1.0050x over previous
//
#include <hip/hip_runtime.h>
#include <math.h>

#define THREADS 256

__device__ __forceinline__ float silu_f(float v) {
    return v / (1.f + __expf(-v));
}

// ---------------------------------------------------------------------------
// Weight transpose: [co][ci][k2] -> [ci][k2][co]  (co contiguous)
// Slice groups (for grid.z kernels) are laid out contiguously (no align
// padding inside a group) so wt + z*CIN*K2*COUT indexes slice z.
// ---------------------------------------------------------------------------
struct TEnt { const float* src; int dst; int cin; int cout; int k2; int base; int n; };
struct TTab { TEnt e[40]; int total; };

__global__ __launch_bounds__(THREADS)
void transpose_w_k(TTab t, float* __restrict__ tw) {
    const int i = blockIdx.x * THREADS + threadIdx.x;
    if (i >= t.total) return;
    int j = 0;
    while (i >= t.e[j].base + t.e[j].n) ++j;
    const TEnt e = t.e[j];
    const int local = i - e.base;
    const int co  = local % e.cout;
    const int tmp = local / e.cout;
    const int k   = tmp % e.k2;
    const int ci  = tmp / e.k2;
    tw[e.dst + local] = e.src[(co * e.cin + ci) * e.k2 + k];
}

// aligned-chunk row loader with edge fallback
template<int KS, int PX>
__device__ __forceinline__ void load_row(float* __restrict__ rr,
                                         const float* __restrict__ rp,
                                         bool vy, int x0, int W)
{
    constexpr int PAD = (KS - 1) / 2;
    constexpr int RW = PX + KS - 1;
#pragma unroll
    for (int q = -1; q <= PX / 4; ++q) {
        if (4 * q + 3 + PAD < 0 || 4 * q + PAD >= RW) continue;
        const int xs = x0 + 4 * q;
        float vc[4] = {0.f, 0.f, 0.f, 0.f};
        if (vy && xs >= 0 && xs + 4 <= W) {
            const float4 v = *reinterpret_cast<const float4*>(rp + xs);
            vc[0] = v.x; vc[1] = v.y; vc[2] = v.z; vc[3] = v.w;
        } else if (vy) {
#pragma unroll
            for (int c = 0; c < 4; ++c)
                vc[c] = ((unsigned)(xs + c) < (unsigned)W) ? rp[xs + c] : 0.f;
        }
#pragma unroll
        for (int c = 0; c < 4; ++c) {
            const int t = 4 * q + c + PAD;
            if (t >= 0 && t < RW) rr[t] = vc[c];
        }
    }
}

// ---------------------------------------------------------------------------
// Sliced direct conv2d: blockIdx.z selects an output-channel slice of COUT.
// Occupancy-first shape (round-8 lesson: 2 waves/SIMD was the wall):
// acc = COUT*PX <= 64 regs, per-ky double-buffered rows (r[2][RW]),
// 2-stage weight prefetch, per-tap sched_barrier(0) (round-4 spill guard).
// ds:FMA per CU = 24*WQ/(COUT*PX) -> 0.75 at CO8/PX8.
// ---------------------------------------------------------------------------
template<int CIN, int COUT, int KS, bool ACT, int PX>
__global__ __launch_bounds__(THREADS)
void conv_sl_k(const float* __restrict__ in, const float* __restrict__ wt,
               const float* __restrict__ bias, float* __restrict__ out,
               int H, int lw, int bs_in, int bs_out)
{
    constexpr int PAD = (KS - 1) / 2;
    constexpr int K2 = KS * KS;
    constexpr int CO_S = (COUT + 3) & ~3;
    constexpr int WQ = CO_S / 4;
    constexpr int RW = PX + KS - 1;
    __shared__ float sw[CIN * K2 * CO_S];

    const int z = blockIdx.z;
    const float* __restrict__ wz = wt + (size_t)z * (CIN * K2 * COUT);
    const int W = 1 << lw;
    const int total = H << lw;
    const int idx = (blockIdx.x * THREADS + threadIdx.x) * PX;
    const float* ip0 = in + (size_t)blockIdx.y * bs_in;
    float* op = out + (size_t)blockIdx.y * bs_out + (size_t)z * COUT * total;
    const int x0 = idx & (W - 1);
    const int y  = idx >> lw;

    for (int i = threadIdx.x; i < CIN * K2 * COUT; i += THREADS) {
        const int co = i % COUT;
        const int rest = i / COUT;
        sw[rest * CO_S + co] = wz[i];
    }
    __syncthreads();

    float acc[COUT][PX];
#pragma unroll
    for (int co = 0; co < COUT; ++co) {
        const float b = bias[z * COUT + co];
#pragma unroll
        for (int j = 0; j < PX; ++j) acc[co][j] = b;
    }

#pragma unroll 1
    for (int cl = 0; cl < CIN; ++cl) {
        const float* __restrict__ row0 = ip0 + (size_t)cl * total;
        float r[2][RW];
        {
            const int yy = y - PAD;
            load_row<KS, PX>(r[0], row0 + (yy << lw), (unsigned)yy < (unsigned)H, x0, W);
        }
        const float* __restrict__ wbase = &sw[cl * K2 * CO_S];
        float4 wb[2][WQ];
#pragma unroll
        for (int q = 0; q < WQ; ++q)
            wb[0][q] = reinterpret_cast<const float4*>(wbase)[q];

#pragma unroll
        for (int ky = 0; ky < KS; ++ky) {
            if (ky + 1 < KS) {           // prefetch next row under this ky's taps
                const int yy = y + ky + 1 - PAD;
                load_row<KS, PX>(r[(ky + 1) & 1], row0 + (yy << lw),
                                 (unsigned)yy < (unsigned)H, x0, W);
            }
#pragma unroll
            for (int kx = 0; kx < KS; ++kx) {
                const int t = ky * KS + kx;
                if (t + 1 < K2) {        // prefetch next tap's weights
                    const float4* __restrict__ nx =
                        reinterpret_cast<const float4*>(wbase + (t + 1) * CO_S);
#pragma unroll
                    for (int q = 0; q < WQ; ++q) wb[(t + 1) & 1][q] = nx[q];
                }
#pragma unroll
                for (int q = 0; q < WQ; ++q) {
                    const float4 w = wb[t & 1][q];
                    const float wc[4] = {w.x, w.y, w.z, w.w};
#pragma unroll
                    for (int c = 0; c < 4; ++c) {
                        const int co = 4 * q + c;
                        if (co < COUT) {
#pragma unroll
                            for (int j = 0; j < PX; ++j)
                                acc[co][j] = fmaf(r[ky & 1][kx + j], wc[c], acc[co][j]);
                        }
                    }
                }
                __builtin_amdgcn_sched_barrier(0);
            }
        }
    }

#pragma unroll
    for (int co = 0; co < COUT; ++co) {
#pragma unroll
        for (int j4 = 0; j4 < PX / 4; ++j4) {
            float4 v;
            v.x = ACT ? silu_f(acc[co][4 * j4 + 0]) : acc[co][4 * j4 + 0];
            v.y = ACT ? silu_f(acc[co][4 * j4 + 1]) : acc[co][4 * j4 + 1];
            v.z = ACT ? silu_f(acc[co][4 * j4 + 2]) : acc[co][4 * j4 + 2];
            v.w = ACT ? silu_f(acc[co][4 * j4 + 3]) : acc[co][4 * j4 + 3];
            *reinterpret_cast<float4*>(op + (size_t)co * total + idx + 4 * j4) = v;
        }
    }
}

// ---------------------------------------------------------------------------
// Generic direct conv2d (round-8 version) for the small/medium convs.
// ---------------------------------------------------------------------------
template<int CIN, int COUT, int KS, bool ACT, int PX>
__global__ __launch_bounds__(THREADS)
void conv_k(const float* __restrict__ in, const float* __restrict__ wt,
            const float* __restrict__ bias, float* __restrict__ out,
            int H, int lw, int bs_in, int bs_out)
{
    constexpr int PAD = (KS - 1) / 2;
    constexpr int K2 = KS * KS;
    constexpr int CO_S = (COUT + 3) & ~3;
    constexpr int WQ = CO_S / 4;
    constexpr int RW = PX + KS - 1;
    __shared__ float sw[CIN * K2 * CO_S];

    const int W = 1 << lw;
    const int total = H << lw;
    const int idx = (blockIdx.x * THREADS + threadIdx.x) * PX;
    const float* ip0 = in + (size_t)blockIdx.y * bs_in;
    float* op = out + (size_t)blockIdx.y * bs_out;
    const int x0 = idx & (W - 1);
    const int y  = idx >> lw;

    for (int i = threadIdx.x; i < CIN * K2 * COUT; i += THREADS) {
        const int co = i % COUT;
        const int rest = i / COUT;
        sw[rest * CO_S + co] = wt[i];
    }
    __syncthreads();

    float acc[COUT][PX];
#pragma unroll
    for (int co = 0; co < COUT; ++co) {
        const float b = bias[co];
#pragma unroll
        for (int j = 0; j < PX; ++j) acc[co][j] = b;
    }

#pragma unroll 1
    for (int cl = 0; cl < CIN; ++cl) {
        const float* __restrict__ row0 = ip0 + (size_t)cl * total;
        float r[KS][RW];
#pragma unroll
        for (int ky = 0; ky < KS; ++ky) {
            const int yy = y + ky - PAD;
            load_row<KS, PX>(r[ky], row0 + (yy << lw), (unsigned)yy < (unsigned)H, x0, W);
        }
        const float* __restrict__ wbase = &sw[cl * K2 * CO_S];
#pragma unroll
        for (int t = 0; t < K2; ++t) {
            const int ky = t / KS, kx = t % KS;
            const float4* __restrict__ wv =
                reinterpret_cast<const float4*>(wbase + t * CO_S);
#pragma unroll
            for (int q = 0; q < WQ; ++q) {
                const float4 w = wv[q];
                const float wc[4] = {w.x, w.y, w.z, w.w};
#pragma unroll
                for (int c = 0; c < 4; ++c) {
                    const int co = 4 * q + c;
                    if (co < COUT) {
#pragma unroll
                        for (int j = 0; j < PX; ++j)
                            acc[co][j] = fmaf(r[ky][kx + j], wc[c], acc[co][j]);
                    }
                }
            }
            __builtin_amdgcn_sched_barrier(0);
        }
    }

#pragma unroll
    for (int co = 0; co < COUT; ++co) {
        if (PX == 2) {
            float2 v;
            v.x = ACT ? silu_f(acc[co][0]) : acc[co][0];
            v.y = ACT ? silu_f(acc[co][1]) : acc[co][1];
            *reinterpret_cast<float2*>(op + (size_t)co * total + idx) = v;
        } else {
#pragma unroll
            for (int j4 = 0; j4 < PX / 4; ++j4) {
                float4 v;
                v.x = ACT ? silu_f(acc[co][4 * j4 + 0]) : acc[co][4 * j4 + 0];
                v.y = ACT ? silu_f(acc[co][4 * j4 + 1]) : acc[co][4 * j4 + 1];
                v.z = ACT ? silu_f(acc[co][4 * j4 + 2]) : acc[co][4 * j4 + 2];
                v.w = ACT ? silu_f(acc[co][4 * j4 + 3]) : acc[co][4 * j4 + 3];
                *reinterpret_cast<float4*>(op + (size_t)co * total + idx + 4 * j4) = v;
            }
        }
    }
}

// ---------------------------------------------------------------------------
// DeformConv2d: 3x3, stride 1, pad 1, no bias. groups=2, offset groups=2.
// ---------------------------------------------------------------------------
template<int CIN, int COUT>
__global__ __launch_bounds__(THREADS)
void dconv_k(const float* __restrict__ in, const float* __restrict__ off,
             const float* __restrict__ twg0, const float* __restrict__ twg1,
             float* __restrict__ out,
             int H, int lw, int bs_in, int bs_off, int bs_out)
{
    constexpr int K = 9;
    constexpr int OG = 2;
    constexpr int COG = CIN / OG;
    constexpr int COUTG = COUT / 2;
    constexpr int NWG = COG * K * COUTG;
    __shared__ float sw[2 * NWG];
    for (int i = threadIdx.x; i < 2 * NWG; i += THREADS)
        sw[i] = (i < NWG) ? twg0[i] : twg1[i - NWG];
    __syncthreads();

    const int W = 1 << lw;
    const int total = H << lw;
    const int idx = blockIdx.x * THREADS + threadIdx.x;
    const float* ip0 = in + (size_t)blockIdx.y * bs_in;
    const float* offp = off + (size_t)blockIdx.y * bs_off;
    float* op = out + (size_t)blockIdx.y * bs_out;
    const int x = idx & (W - 1);
    const int y = idx >> lw;

    float acc[COUT];
#pragma unroll
    for (int co = 0; co < COUT; ++co) acc[co] = 0.f;

#pragma unroll
    for (int og = 0; og < OG; ++og) {
#pragma unroll
        for (int k = 0; k < K; ++k) {
            const int ki = k / 3 - 1;
            const int kj = k % 3 - 1;
            const float dy = offp[(size_t)(((og * K + k) * 2 + 0)) * total + idx];
            const float dx = offp[(size_t)(((og * K + k) * 2 + 1)) * total + idx];
            const float py = dy + (float)(y + ki);
            const float px = dx + (float)(x + kj);
            const float y0f = floorf(py), x0f = floorf(px);
            const float ly = py - y0f, lx = px - x0f;
            const int y0 = (int)y0f, x0 = (int)x0f;
            const int y1 = y0 + 1, x1 = x0 + 1;
            const bool vy0 = (unsigned)y0 < (unsigned)H;
            const bool vy1 = (unsigned)y1 < (unsigned)H;
            const bool vx0 = (unsigned)x0 < (unsigned)W;
            const bool vx1 = (unsigned)x1 < (unsigned)W;
            const int cy0 = min(max(y0, 0), H - 1), cy1 = min(max(y1, 0), H - 1);
            const int cx0 = min(max(x0, 0), W - 1), cx1 = min(max(x1, 0), W - 1);
            const int i00 = (cy0 << lw) + cx0, i01 = (cy0 << lw) + cx1;
            const int i10 = (cy1 << lw) + cx0, i11 = (cy1 << lw) + cx1;
            const float f00 = (vy0 && vx0) ? (1.f - ly) * (1.f - lx) : 0.f;
            const float f01 = (vy0 && vx1) ? (1.f - ly) * lx : 0.f;
            const float f10 = (vy1 && vx0) ? ly * (1.f - lx) : 0.f;
            const float f11 = (vy1 && vx1) ? ly * lx : 0.f;
            const float* swg = &sw[og * NWG];
#pragma unroll
            for (int c = 0; c < COG; ++c) {
                const float* __restrict__ ip = ip0 + (size_t)(og * COG + c) * total;
                const float v = f00 * ip[i00] + f01 * ip[i01]
                              + f10 * ip[i10] + f11 * ip[i11];
                const float* __restrict__ wr = &swg[(c * K + k) * COUTG];
#pragma unroll
                for (int col = 0; col < COUTG; ++col)
                    acc[og * COUTG + col] = fmaf(v, wr[col], acc[og * COUTG + col]);
            }
        }
    }

#pragma unroll
    for (int co = 0; co < COUT; ++co)
        op[(size_t)co * total + idx] = acc[co];
}

// 2x2 average pool.
__global__ __launch_bounds__(THREADS)
void avgpool_k(const float* __restrict__ in, float* __restrict__ out,
               int n, int lt, int lwo, int bsi, int bso)
{
    const int idx = blockIdx.x * THREADS + threadIdx.x;
    if (idx >= n) return;
    const float* ip0 = in + (size_t)blockIdx.y * bsi;
    float* op = out + (size_t)blockIdx.y * bso;
    const int c = idx >> lt;
    const int r = idx & ((1 << lt) - 1);
    const int oy = r >> lwo;
    const int ox = r & ((1 << lwo) - 1);
    const int Wi = 2 << lwo;
    const float* ip = ip0 + ((size_t)c << (lt + 2)) + ((size_t)(2 * oy) << (lwo + 1)) + 2 * ox;
    const float2 t = *reinterpret_cast<const float2*>(ip);
    const float2 b = *reinterpret_cast<const float2*>(ip + Wi);
    op[idx] = 0.25f * (t.x + t.y + b.x + b.y);
}

// Bilinear 2x upsample, align_corners=True.
__global__ __launch_bounds__(THREADS)
void up2x_k(const float* __restrict__ in, float* __restrict__ out,
            int n, int lt, int lwo, int Hin, int bsi, int bso)
{
    const int idx = blockIdx.x * THREADS + threadIdx.x;
    if (idx >= n) return;
    const float* ip0 = in + (size_t)blockIdx.y * bsi;
    float* op = out + (size_t)blockIdx.y * bso;
    const int c = idx >> lt;
    const int r = idx & ((1 << lt) - 1);
    const int oy = r >> lwo;
    const int ox = r & ((1 << lwo) - 1);
    const int W = 1 << (lwo - 1);
    const int H = Hin;
    const float s = (float)(H - 1) / (float)(2 * H - 1);
    const float fy = (float)oy * s;
    const float fx = (float)ox * s;
    const int y0 = (int)fy;
    const int x0 = (int)fx;
    const int y1 = min(y0 + 1, H - 1);
    const int x1 = min(x0 + 1, W - 1);
    const float wy = fy - (float)y0;
    const float wx = fx - (float)x0;
    const float* ip = ip0 + ((size_t)c << (lt - 2));
    const float v00 = ip[y0 * W + x0], v01 = ip[y0 * W + x1];
    const float v10 = ip[y1 * W + x0], v11 = ip[y1 * W + x1];
    op[idx] = (v00 * (1.f - wy) + v10 * wy) * (1.f - wx)
            + (v01 * (1.f - wy) + v11 * wy) * wx;
}

// strided batched d2d copy (float4 granularity)
__global__ __launch_bounds__(THREADS)
void copy_k(float4* __restrict__ dst, const float4* __restrict__ src,
            int n4, int bsd, int bss)
{
    const int i = blockIdx.x * THREADS + threadIdx.x;
    if (i >= n4) return;
    dst[(size_t)blockIdx.y * bsd + i] = src[(size_t)blockIdx.y * bss + i];
}

// ---------------------------------------------------------------------------

extern "C" void kernel_launch(void* const* d_in, const int* in_sizes, int n_in,
                              void* d_out, int out_size, void* d_ws, size_t ws_size,
                              hipStream_t stream) {
    const float* x      = (const float*)d_in[0];
    const float* eo1_b1 = (const float*)d_in[2];
    const float* eo1_b2 = (const float*)d_in[4];
    const float* c1d_b1 = (const float*)d_in[7];
    const float* c1d_b2 = (const float*)d_in[9];
    const float* eo2_b1 = (const float*)d_in[11];
    const float* eo2_b2 = (const float*)d_in[13];
    const float* c2d_b1 = (const float*)d_in[16];
    const float* c2d_b2 = (const float*)d_in[18];
    const float* eo3_b1 = (const float*)d_in[20];
    const float* eo3_b2 = (const float*)d_in[22];
    const float* c3d_b1 = (const float*)d_in[25];
    const float* c3d_b2 = (const float*)d_in[27];
    const float* up2_b  = (const float*)d_in[29];
    const float* c2u_b1 = (const float*)d_in[31];
    const float* c2u_b2 = (const float*)d_in[33];
    const float* up1_b  = (const float*)d_in[35];
    const float* c1u_b1 = (const float*)d_in[37];
    const float* c1u_b2 = (const float*)d_in[39];

    float* out = (float*)d_out;
    float* wsf = (float*)d_ws;

    constexpr int H1 = 512, A1 = H1 * H1;
    constexpr int H2 = 256, A2 = H2 * H2;
    constexpr int H3 = 128, A3 = H3 * H3;
    constexpr int TW_FLOATS = 81920;
    constexpr int SLOT = 58 * A1;

    // ---- transposed-weight table: 29 conv entries + 6 dconv groups ----
    // slices: eo1_w1 -> 3x(4,6,25); eo1_b2/eo2_b2 -> 4x(18,8,25)+(18,4,25)
    const int widx[29]  = {1, 1, 1,  3, 3, 3, 3, 3,  6, 8, 10,
                           12, 12, 12, 12, 12,  19, 21, 21,
                           15, 17, 24, 26, 28, 30, 32, 34, 36, 38};
    const int wcin[29]  = {4, 4, 4,  18, 18, 18, 18, 18,  2, 4, 8,
                           18, 18, 18, 18, 18,  16, 18, 18,
                           8, 12, 16, 14, 12, 28, 16, 8, 16, 8};
    const int wcout[29] = {6, 6, 6,  8, 8, 8, 8, 4,  4, 8, 18,
                           8, 8, 8, 8, 4,  18, 18, 18,
                           12, 16, 14, 12, 12, 16, 8, 8, 8, 2};
    const int wk2[29]   = {25, 25, 25,  25, 25, 25, 25, 25,  9, 9, 25,
                           25, 25, 25, 25, 25,  25, 25, 25,
                           9, 9, 9, 9, 9, 9, 9, 9, 9, 9};
    const int wsoff[29] = {0, 600, 1200,  0, 3600, 7200, 10800, 14400,  0, 0, 0,
                           0, 3600, 7200, 10800, 14400,  0, 0, 8100,
                           0, 0, 0, 0, 0, 0, 0, 0, 0, 0};
    // cont[i]=1: next entry contiguous (same slice group, no align padding)
    const int cont[29]  = {1, 1, 0,  1, 1, 1, 0, 0,  0, 0, 0,
                           1, 1, 1, 0, 0,  0, 0, 0,
                           0, 0, 0, 0, 0, 0, 0, 0, 0, 0};
    TTab tab;
    const float* tw[35];
    int off = 0, base = 0;
    for (int i = 0; i < 29; ++i) {
        const int n = wcin[i] * wcout[i] * wk2[i];
        tab.e[i].src = (const float*)d_in[widx[i]] + wsoff[i];
        tab.e[i].dst = off; tab.e[i].cin = wcin[i]; tab.e[i].cout = wcout[i];
        tab.e[i].k2 = wk2[i]; tab.e[i].base = base; tab.e[i].n = n;
        tw[i] = wsf + off;
        off = cont[i] ? (off + n) : ((off + n + 63) & ~63);
        base += n;
    }
    const int didx[3]   = {5, 14, 23};
    const int dcoutg[3] = {1, 4, 8};
    const int dcpg[3]   = {2, 4, 8};
    for (int i = 0; i < 3; ++i) {
        for (int g = 0; g < 2; ++g) {
            const int e = 29 + 2 * i + g;
            const int n = dcoutg[i] * dcpg[i] * 9;
            tab.e[e].src = (const float*)d_in[didx[i]] + (size_t)g * n;
            tab.e[e].dst = off; tab.e[e].cin = dcpg[i]; tab.e[e].cout = dcoutg[i];
            tab.e[e].k2 = 9; tab.e[e].base = base; tab.e[e].n = n;
            tw[e] = wsf + off;
            off = (off + n + 63) & ~63;
            base += n;
        }
    }
    tab.total = base;
    transpose_w_k<<<(base + THREADS - 1) / THREADS, THREADS, 0, stream>>>(tab, wsf);

    int B = 4;
    while (B > 1 && ws_size < ((size_t)TW_FLOATS + (size_t)B * SLOT) * sizeof(float)) B >>= 1;

    auto run_all = [&](int Bc, float* slot, int SB,
                       const float* xin, int xbs, float* outp, int obs) {
        float* S0 = slot;                // 36*A1
        float* S1 = S0 + 36 * A1;        // 18*A1
        float* S2 = S1 + 18 * A1;        //  2*A1
        float* P  = S2 + 2 * A1;         //  2*A1
        float* L1 = S1 + 10 * A1;        //  8*A1 tail of S1 (conv1_d skip)
        float* L2 = S0 + 32 * A1;        //  4*A1 tail of S0 (conv2_d skip)
        auto gz = [&](int n, int px, int z) { return dim3(n / (px * THREADS), Bc, z); };
        auto gp = [&](int n, int px) { return dim3(n / (px * THREADS), Bc); };
        auto g1 = [&](int n) { return dim3((n + THREADS - 1) / THREADS, Bc); };

        // ---- level 1 down ----
        conv_sl_k<4, 6, 5, false, 8><<<gz(A1, 8, 3), THREADS, 0, stream>>>(xin, tw[0], eo1_b1, S1, H1, 9, xbs, SB);
        conv_sl_k<18, 8, 5, false, 8><<<gz(A1, 8, 4), THREADS, 0, stream>>>(S1, tw[3], eo1_b2, S0, H1, 9, SB, SB);
        conv_sl_k<18, 4, 5, false, 8><<<gz(A1, 8, 1), THREADS, 0, stream>>>(S1, tw[7], eo1_b2 + 32, S0 + 32 * A1, H1, 9, SB, SB);
        dconv_k<4, 2><<<g1(A1), THREADS, 0, stream>>>(xin, S0, tw[29], tw[30], S2, H1, 9, xbs, SB, SB);
        conv_k<2, 4, 3, true, 4><<<gp(A1, 4), THREADS, 0, stream>>>(S2, tw[8], c1d_b1, S1, H1, 9, SB, SB);
        conv_k<4, 8, 3, true, 4><<<gp(A1, 4), THREADS, 0, stream>>>(S1, tw[9], c1d_b2, L1, H1, 9, SB, SB);
        avgpool_k<<<g1(8 * A2), THREADS, 0, stream>>>(L1, P, 8 * A2, 16, 8, SB, SB);

        // ---- level 2 down ----
        conv_k<8, 18, 5, false, 2><<<gp(A2, 2), THREADS, 0, stream>>>(P, tw[10], eo2_b1, S1, H2, 8, SB, SB);
        conv_sl_k<18, 8, 5, false, 4><<<gz(A2, 4, 4), THREADS, 0, stream>>>(S1, tw[11], eo2_b2, S0, H2, 8, SB, SB);
        conv_sl_k<18, 4, 5, false, 4><<<gz(A2, 4, 1), THREADS, 0, stream>>>(S1, tw[15], eo2_b2 + 32, S0 + 32 * A2, H2, 8, SB, SB);
        dconv_k<8, 8><<<g1(A2), THREADS, 0, stream>>>(P, S0, tw[31], tw[32], S2, H2, 8, SB, SB, SB);
        conv_k<8, 12, 3, true, 2><<<gp(A2, 2), THREADS, 0, stream>>>(S2, tw[19], c2d_b1, S1, H2, 8, SB, SB);
        conv_k<12, 16, 3, true, 2><<<gp(A2, 2), THREADS, 0, stream>>>(S1, tw[20], c2d_b2, L2, H2, 8, SB, SB);
        avgpool_k<<<g1(16 * A3), THREADS, 0, stream>>>(L2, P, 16 * A3, 14, 7, SB, SB);

        // ---- level 3 (bottleneck) ----
        conv_k<16, 18, 5, false, 2><<<gp(A3, 2), THREADS, 0, stream>>>(P, tw[16], eo3_b1, S1, H3, 7, SB, SB);
        conv_k<18, 18, 5, false, 2><<<gp(A3, 2), THREADS, 0, stream>>>(S1, tw[17], eo3_b2, S0, H3, 7, SB, SB);
        conv_k<18, 18, 5, false, 2><<<gp(A3, 2), THREADS, 0, stream>>>(S1, tw[18], eo3_b2 + 18, S0 + 18 * A3, H3, 7, SB, SB);
        dconv_k<16, 16><<<g1(A3), THREADS, 0, stream>>>(P, S0, tw[33], tw[34], S2, H3, 7, SB, SB, SB);
        conv_k<16, 14, 3, true, 2><<<gp(A3, 2), THREADS, 0, stream>>>(S2, tw[21], c3d_b1, S1, H3, 7, SB, SB);
        conv_k<14, 12, 3, true, 2><<<gp(A3, 2), THREADS, 0, stream>>>(S1, tw[22], c3d_b2, S2, H3, 7, SB, SB);

        // ---- up path level 2 ----
        up2x_k<<<g1(12 * A2), THREADS, 0, stream>>>(S2, S0, 12 * A2, 16, 8, H3, SB, SB);
        conv_k<12, 12, 3, true, 2><<<gp(A2, 2), THREADS, 0, stream>>>(S0, tw[23], up2_b, S1, H2, 8, SB, SB);
        copy_k<<<g1(4 * A2), THREADS, 0, stream>>>((float4*)(S1 + 12 * A2), (const float4*)L2,
                                                   4 * A2, SB / 4, SB / 4);
        conv_k<28, 16, 3, true, 2><<<gp(A2, 2), THREADS, 0, stream>>>(S1, tw[24], c2u_b1, S0, H2, 8, SB, SB);
        conv_k<16, 8, 3, true, 2><<<gp(A2, 2), THREADS, 0, stream>>>(S0, tw[25], c2u_b2, S2, H2, 8, SB, SB);

        // ---- up path level 1 ----
        up2x_k<<<g1(8 * A1), THREADS, 0, stream>>>(S2, S0, 8 * A1, 18, 9, H2, SB, SB);
        conv_k<8, 8, 3, true, 4><<<gp(A1, 4), THREADS, 0, stream>>>(S0, tw[26], up1_b, S0 + 8 * A1, H1, 9, SB, SB);
        copy_k<<<g1(2 * A1), THREADS, 0, stream>>>((float4*)(S0 + 16 * A1), (const float4*)L1,
                                                   2 * A1, SB / 4, SB / 4);
        conv_k<16, 8, 3, true, 4><<<gp(A1, 4), THREADS, 0, stream>>>(S0 + 8 * A1, tw[27], c1u_b1, S1, H1, 9, SB, SB);
        conv_k<8, 2, 3, true, 4><<<gp(A1, 4), THREADS, 0, stream>>>(S1, tw[28], c1u_b2, outp, H1, 9, SB, obs);
    };

    for (int g = 0; g < 4; g += B)
        run_all(B, wsf + TW_FLOATS, SLOT,
                x + (size_t)g * 4 * A1, 4 * A1,
                out + (size_t)g * 2 * A1, 2 * A1);
}

// Round 10
// 1938.774 us; speedup vs baseline: 1.4213x; 1.0274x over previous
//
#include <hip/hip_runtime.h>
#include <math.h>

#define THREADS 256

__device__ __forceinline__ float silu_f(float v) {
    return v / (1.f + __expf(-v));
}

// ---------------------------------------------------------------------------
// Weight transpose: [co][ci][k2] -> [ci][k2][co]  (co contiguous)
// Slice groups are contiguous (no align padding inside a group) so
// wt + z*CIN*K2*COUT indexes slice z.
// ---------------------------------------------------------------------------
struct TEnt { const float* src; int dst; int cin; int cout; int k2; int base; int n; };
struct TTab { TEnt e[40]; int total; };

__global__ __launch_bounds__(THREADS)
void transpose_w_k(TTab t, float* __restrict__ tw) {
    const int i = blockIdx.x * THREADS + threadIdx.x;
    if (i >= t.total) return;
    int j = 0;
    while (i >= t.e[j].base + t.e[j].n) ++j;
    const TEnt e = t.e[j];
    const int local = i - e.base;
    const int co  = local % e.cout;
    const int tmp = local / e.cout;
    const int k   = tmp % e.k2;
    const int ci  = tmp / e.k2;
    tw[e.dst + local] = e.src[(co * e.cin + ci) * e.k2 + k];
}

// aligned-chunk row loader with edge fallback
template<int KS, int PX>
__device__ __forceinline__ void load_row(float* __restrict__ rr,
                                         const float* __restrict__ rp,
                                         bool vy, int x0, int W)
{
    constexpr int PAD = (KS - 1) / 2;
    constexpr int RW = PX + KS - 1;
#pragma unroll
    for (int q = -1; q <= PX / 4; ++q) {
        if (4 * q + 3 + PAD < 0 || 4 * q + PAD >= RW) continue;
        const int xs = x0 + 4 * q;
        float vc[4] = {0.f, 0.f, 0.f, 0.f};
        if (vy && xs >= 0 && xs + 4 <= W) {
            const float4 v = *reinterpret_cast<const float4*>(rp + xs);
            vc[0] = v.x; vc[1] = v.y; vc[2] = v.z; vc[3] = v.w;
        } else if (vy) {
#pragma unroll
            for (int c = 0; c < 4; ++c)
                vc[c] = ((unsigned)(xs + c) < (unsigned)W) ? rp[xs + c] : 0.f;
        }
#pragma unroll
        for (int c = 0; c < 4; ++c) {
            const int t = 4 * q + c + PAD;
            if (t >= 0 && t < RW) rr[t] = vc[c];
        }
    }
}

// ---------------------------------------------------------------------------
// Sliced direct conv2d, 1-D grid: lin = z + NZ*(b + NB*xblk).
// Slice z is the FASTEST dim so the NZ blocks re-reading identical input run
// back-to-back and hit L2/L3 (round-9 lesson: z-slowest dispatch order
// streamed 300 MB between reuses -> 4x HBM re-fetch).
// acc = COUT*PX <= 64 regs, double-buffered rows, 2-stage weight prefetch,
// per-tap sched_barrier(0) (round-4 spill guard).
// ---------------------------------------------------------------------------
template<int CIN, int COUT, int KS, bool ACT, int PX>
__global__ __launch_bounds__(THREADS)
void conv_sl_k(const float* __restrict__ in, const float* __restrict__ wt,
               const float* __restrict__ bias, float* __restrict__ out,
               int H, int lw, int bs_in, int bs_out, int nb, int nz)
{
    constexpr int PAD = (KS - 1) / 2;
    constexpr int K2 = KS * KS;
    constexpr int CO_S = (COUT + 3) & ~3;
    constexpr int WQ = CO_S / 4;
    constexpr int RW = PX + KS - 1;
    __shared__ float sw[CIN * K2 * CO_S];

    int lin = blockIdx.x;
    const int z = lin % nz; lin /= nz;
    const int b = lin % nb; lin /= nb;
    const int xb = lin;

    const float* __restrict__ wz = wt + (size_t)z * (CIN * K2 * COUT);
    const int W = 1 << lw;
    const int total = H << lw;
    const int idx = (xb * THREADS + threadIdx.x) * PX;
    const float* ip0 = in + (size_t)b * bs_in;
    float* op = out + (size_t)b * bs_out + (size_t)z * COUT * total;
    const int x0 = idx & (W - 1);
    const int y  = idx >> lw;

    for (int i = threadIdx.x; i < CIN * K2 * COUT; i += THREADS) {
        const int co = i % COUT;
        const int rest = i / COUT;
        sw[rest * CO_S + co] = wz[i];
    }
    __syncthreads();

    float acc[COUT][PX];
#pragma unroll
    for (int co = 0; co < COUT; ++co) {
        const float bb = bias[z * COUT + co];
#pragma unroll
        for (int j = 0; j < PX; ++j) acc[co][j] = bb;
    }

#pragma unroll 1
    for (int cl = 0; cl < CIN; ++cl) {
        const float* __restrict__ row0 = ip0 + (size_t)cl * total;
        float r[2][RW];
        {
            const int yy = y - PAD;
            load_row<KS, PX>(r[0], row0 + (yy << lw), (unsigned)yy < (unsigned)H, x0, W);
        }
        const float* __restrict__ wbase = &sw[cl * K2 * CO_S];
        float4 wb[2][WQ];
#pragma unroll
        for (int q = 0; q < WQ; ++q)
            wb[0][q] = reinterpret_cast<const float4*>(wbase)[q];

#pragma unroll
        for (int ky = 0; ky < KS; ++ky) {
            if (ky + 1 < KS) {
                const int yy = y + ky + 1 - PAD;
                load_row<KS, PX>(r[(ky + 1) & 1], row0 + (yy << lw),
                                 (unsigned)yy < (unsigned)H, x0, W);
            }
#pragma unroll
            for (int kx = 0; kx < KS; ++kx) {
                const int t = ky * KS + kx;
                if (t + 1 < K2) {
                    const float4* __restrict__ nx =
                        reinterpret_cast<const float4*>(wbase + (t + 1) * CO_S);
#pragma unroll
                    for (int q = 0; q < WQ; ++q) wb[(t + 1) & 1][q] = nx[q];
                }
#pragma unroll
                for (int q = 0; q < WQ; ++q) {
                    const float4 w = wb[t & 1][q];
                    const float wc[4] = {w.x, w.y, w.z, w.w};
#pragma unroll
                    for (int c = 0; c < 4; ++c) {
                        const int co = 4 * q + c;
                        if (co < COUT) {
#pragma unroll
                            for (int j = 0; j < PX; ++j)
                                acc[co][j] = fmaf(r[ky & 1][kx + j], wc[c], acc[co][j]);
                        }
                    }
                }
                __builtin_amdgcn_sched_barrier(0);
            }
        }
    }

#pragma unroll
    for (int co = 0; co < COUT; ++co) {
#pragma unroll
        for (int j4 = 0; j4 < PX / 4; ++j4) {
            float4 v;
            v.x = ACT ? silu_f(acc[co][4 * j4 + 0]) : acc[co][4 * j4 + 0];
            v.y = ACT ? silu_f(acc[co][4 * j4 + 1]) : acc[co][4 * j4 + 1];
            v.z = ACT ? silu_f(acc[co][4 * j4 + 2]) : acc[co][4 * j4 + 2];
            v.w = ACT ? silu_f(acc[co][4 * j4 + 3]) : acc[co][4 * j4 + 3];
            *reinterpret_cast<float4*>(op + (size_t)co * total + idx + 4 * j4) = v;
        }
    }
}

// ---------------------------------------------------------------------------
// Generic direct conv2d for the small/medium convs (grid.y = batch).
// ---------------------------------------------------------------------------
template<int CIN, int COUT, int KS, bool ACT, int PX>
__global__ __launch_bounds__(THREADS)
void conv_k(const float* __restrict__ in, const float* __restrict__ wt,
            const float* __restrict__ bias, float* __restrict__ out,
            int H, int lw, int bs_in, int bs_out)
{
    constexpr int PAD = (KS - 1) / 2;
    constexpr int K2 = KS * KS;
    constexpr int CO_S = (COUT + 3) & ~3;
    constexpr int WQ = CO_S / 4;
    constexpr int RW = PX + KS - 1;
    __shared__ float sw[CIN * K2 * CO_S];

    const int W = 1 << lw;
    const int total = H << lw;
    const int idx = (blockIdx.x * THREADS + threadIdx.x) * PX;
    const float* ip0 = in + (size_t)blockIdx.y * bs_in;
    float* op = out + (size_t)blockIdx.y * bs_out;
    const int x0 = idx & (W - 1);
    const int y  = idx >> lw;

    for (int i = threadIdx.x; i < CIN * K2 * COUT; i += THREADS) {
        const int co = i % COUT;
        const int rest = i / COUT;
        sw[rest * CO_S + co] = wt[i];
    }
    __syncthreads();

    float acc[COUT][PX];
#pragma unroll
    for (int co = 0; co < COUT; ++co) {
        const float b = bias[co];
#pragma unroll
        for (int j = 0; j < PX; ++j) acc[co][j] = b;
    }

#pragma unroll 1
    for (int cl = 0; cl < CIN; ++cl) {
        const float* __restrict__ row0 = ip0 + (size_t)cl * total;
        float r[KS][RW];
#pragma unroll
        for (int ky = 0; ky < KS; ++ky) {
            const int yy = y + ky - PAD;
            load_row<KS, PX>(r[ky], row0 + (yy << lw), (unsigned)yy < (unsigned)H, x0, W);
        }
        const float* __restrict__ wbase = &sw[cl * K2 * CO_S];
#pragma unroll
        for (int t = 0; t < K2; ++t) {
            const int ky = t / KS, kx = t % KS;
            const float4* __restrict__ wv =
                reinterpret_cast<const float4*>(wbase + t * CO_S);
#pragma unroll
            for (int q = 0; q < WQ; ++q) {
                const float4 w = wv[q];
                const float wc[4] = {w.x, w.y, w.z, w.w};
#pragma unroll
                for (int c = 0; c < 4; ++c) {
                    const int co = 4 * q + c;
                    if (co < COUT) {
#pragma unroll
                        for (int j = 0; j < PX; ++j)
                            acc[co][j] = fmaf(r[ky][kx + j], wc[c], acc[co][j]);
                    }
                }
            }
            __builtin_amdgcn_sched_barrier(0);
        }
    }

#pragma unroll
    for (int co = 0; co < COUT; ++co) {
        if (PX == 2) {
            float2 v;
            v.x = ACT ? silu_f(acc[co][0]) : acc[co][0];
            v.y = ACT ? silu_f(acc[co][1]) : acc[co][1];
            *reinterpret_cast<float2*>(op + (size_t)co * total + idx) = v;
        } else {
#pragma unroll
            for (int j4 = 0; j4 < PX / 4; ++j4) {
                float4 v;
                v.x = ACT ? silu_f(acc[co][4 * j4 + 0]) : acc[co][4 * j4 + 0];
                v.y = ACT ? silu_f(acc[co][4 * j4 + 1]) : acc[co][4 * j4 + 1];
                v.z = ACT ? silu_f(acc[co][4 * j4 + 2]) : acc[co][4 * j4 + 2];
                v.w = ACT ? silu_f(acc[co][4 * j4 + 3]) : acc[co][4 * j4 + 3];
                *reinterpret_cast<float4*>(op + (size_t)co * total + idx + 4 * j4) = v;
            }
        }
    }
}

// ---------------------------------------------------------------------------
// DeformConv2d: 3x3, stride 1, pad 1, no bias. groups=2, offset groups=2.
// ---------------------------------------------------------------------------
template<int CIN, int COUT>
__global__ __launch_bounds__(THREADS)
void dconv_k(const float* __restrict__ in, const float* __restrict__ off,
             const float* __restrict__ twg0, const float* __restrict__ twg1,
             float* __restrict__ out,
             int H, int lw, int bs_in, int bs_off, int bs_out)
{
    constexpr int K = 9;
    constexpr int OG = 2;
    constexpr int COG = CIN / OG;
    constexpr int COUTG = COUT / 2;
    constexpr int NWG = COG * K * COUTG;
    __shared__ float sw[2 * NWG];
    for (int i = threadIdx.x; i < 2 * NWG; i += THREADS)
        sw[i] = (i < NWG) ? twg0[i] : twg1[i - NWG];
    __syncthreads();

    const int W = 1 << lw;
    const int total = H << lw;
    const int idx = blockIdx.x * THREADS + threadIdx.x;
    const float* ip0 = in + (size_t)blockIdx.y * bs_in;
    const float* offp = off + (size_t)blockIdx.y * bs_off;
    float* op = out + (size_t)blockIdx.y * bs_out;
    const int x = idx & (W - 1);
    const int y = idx >> lw;

    float acc[COUT];
#pragma unroll
    for (int co = 0; co < COUT; ++co) acc[co] = 0.f;

#pragma unroll
    for (int og = 0; og < OG; ++og) {
#pragma unroll
        for (int k = 0; k < K; ++k) {
            const int ki = k / 3 - 1;
            const int kj = k % 3 - 1;
            const float dy = offp[(size_t)(((og * K + k) * 2 + 0)) * total + idx];
            const float dx = offp[(size_t)(((og * K + k) * 2 + 1)) * total + idx];
            const float py = dy + (float)(y + ki);
            const float px = dx + (float)(x + kj);
            const float y0f = floorf(py), x0f = floorf(px);
            const float ly = py - y0f, lx = px - x0f;
            const int y0 = (int)y0f, x0 = (int)x0f;
            const int y1 = y0 + 1, x1 = x0 + 1;
            const bool vy0 = (unsigned)y0 < (unsigned)H;
            const bool vy1 = (unsigned)y1 < (unsigned)H;
            const bool vx0 = (unsigned)x0 < (unsigned)W;
            const bool vx1 = (unsigned)x1 < (unsigned)W;
            const int cy0 = min(max(y0, 0), H - 1), cy1 = min(max(y1, 0), H - 1);
            const int cx0 = min(max(x0, 0), W - 1), cx1 = min(max(x1, 0), W - 1);
            const int i00 = (cy0 << lw) + cx0, i01 = (cy0 << lw) + cx1;
            const int i10 = (cy1 << lw) + cx0, i11 = (cy1 << lw) + cx1;
            const float f00 = (vy0 && vx0) ? (1.f - ly) * (1.f - lx) : 0.f;
            const float f01 = (vy0 && vx1) ? (1.f - ly) * lx : 0.f;
            const float f10 = (vy1 && vx0) ? ly * (1.f - lx) : 0.f;
            const float f11 = (vy1 && vx1) ? ly * lx : 0.f;
            const float* swg = &sw[og * NWG];
#pragma unroll
            for (int c = 0; c < COG; ++c) {
                const float* __restrict__ ip = ip0 + (size_t)(og * COG + c) * total;
                const float v = f00 * ip[i00] + f01 * ip[i01]
                              + f10 * ip[i10] + f11 * ip[i11];
                const float* __restrict__ wr = &swg[(c * K + k) * COUTG];
#pragma unroll
                for (int col = 0; col < COUTG; ++col)
                    acc[og * COUTG + col] = fmaf(v, wr[col], acc[og * COUTG + col]);
            }
        }
    }

#pragma unroll
    for (int co = 0; co < COUT; ++co)
        op[(size_t)co * total + idx] = acc[co];
}

// 2x2 average pool.
__global__ __launch_bounds__(THREADS)
void avgpool_k(const float* __restrict__ in, float* __restrict__ out,
               int n, int lt, int lwo, int bsi, int bso)
{
    const int idx = blockIdx.x * THREADS + threadIdx.x;
    if (idx >= n) return;
    const float* ip0 = in + (size_t)blockIdx.y * bsi;
    float* op = out + (size_t)blockIdx.y * bso;
    const int c = idx >> lt;
    const int r = idx & ((1 << lt) - 1);
    const int oy = r >> lwo;
    const int ox = r & ((1 << lwo) - 1);
    const int Wi = 2 << lwo;
    const float* ip = ip0 + ((size_t)c << (lt + 2)) + ((size_t)(2 * oy) << (lwo + 1)) + 2 * ox;
    const float2 t = *reinterpret_cast<const float2*>(ip);
    const float2 b = *reinterpret_cast<const float2*>(ip + Wi);
    op[idx] = 0.25f * (t.x + t.y + b.x + b.y);
}

// Bilinear 2x upsample, align_corners=True.
__global__ __launch_bounds__(THREADS)
void up2x_k(const float* __restrict__ in, float* __restrict__ out,
            int n, int lt, int lwo, int Hin, int bsi, int bso)
{
    const int idx = blockIdx.x * THREADS + threadIdx.x;
    if (idx >= n) return;
    const float* ip0 = in + (size_t)blockIdx.y * bsi;
    float* op = out + (size_t)blockIdx.y * bso;
    const int c = idx >> lt;
    const int r = idx & ((1 << lt) - 1);
    const int oy = r >> lwo;
    const int ox = r & ((1 << lwo) - 1);
    const int W = 1 << (lwo - 1);
    const int H = Hin;
    const float s = (float)(H - 1) / (float)(2 * H - 1);
    const float fy = (float)oy * s;
    const float fx = (float)ox * s;
    const int y0 = (int)fy;
    const int x0 = (int)fx;
    const int y1 = min(y0 + 1, H - 1);
    const int x1 = min(x0 + 1, W - 1);
    const float wy = fy - (float)y0;
    const float wx = fx - (float)x0;
    const float* ip = ip0 + ((size_t)c << (lt - 2));
    const float v00 = ip[y0 * W + x0], v01 = ip[y0 * W + x1];
    const float v10 = ip[y1 * W + x0], v11 = ip[y1 * W + x1];
    op[idx] = (v00 * (1.f - wy) + v10 * wy) * (1.f - wx)
            + (v01 * (1.f - wy) + v11 * wy) * wx;
}

// strided batched d2d copy (float4 granularity)
__global__ __launch_bounds__(THREADS)
void copy_k(float4* __restrict__ dst, const float4* __restrict__ src,
            int n4, int bsd, int bss)
{
    const int i = blockIdx.x * THREADS + threadIdx.x;
    if (i >= n4) return;
    dst[(size_t)blockIdx.y * bsd + i] = src[(size_t)blockIdx.y * bss + i];
}

// ---------------------------------------------------------------------------

extern "C" void kernel_launch(void* const* d_in, const int* in_sizes, int n_in,
                              void* d_out, int out_size, void* d_ws, size_t ws_size,
                              hipStream_t stream) {
    const float* x      = (const float*)d_in[0];
    const float* eo1_b1 = (const float*)d_in[2];
    const float* eo1_b2 = (const float*)d_in[4];
    const float* c1d_b1 = (const float*)d_in[7];
    const float* c1d_b2 = (const float*)d_in[9];
    const float* eo2_b1 = (const float*)d_in[11];
    const float* eo2_b2 = (const float*)d_in[13];
    const float* c2d_b1 = (const float*)d_in[16];
    const float* c2d_b2 = (const float*)d_in[18];
    const float* eo3_b1 = (const float*)d_in[20];
    const float* eo3_b2 = (const float*)d_in[22];
    const float* c3d_b1 = (const float*)d_in[25];
    const float* c3d_b2 = (const float*)d_in[27];
    const float* up2_b  = (const float*)d_in[29];
    const float* c2u_b1 = (const float*)d_in[31];
    const float* c2u_b2 = (const float*)d_in[33];
    const float* up1_b  = (const float*)d_in[35];
    const float* c1u_b1 = (const float*)d_in[37];
    const float* c1u_b2 = (const float*)d_in[39];

    float* out = (float*)d_out;
    float* wsf = (float*)d_ws;

    constexpr int H1 = 512, A1 = H1 * H1;
    constexpr int H2 = 256, A2 = H2 * H2;
    constexpr int H3 = 128, A3 = H3 * H3;
    constexpr int TW_FLOATS = 81920;
    constexpr int SLOT = 58 * A1;

    // ---- transposed-weight table: 34 conv entries + 6 dconv groups ----
    // slice groups (cont=1 chains): eo1_w1 3xCO6 | eo1_b2 4xCO8 (+CO4) |
    // eo2_w1 3xCO6 | eo2_b2 4xCO8 (+CO4) | eo3_b2 4xCO8 (+CO4)
    const int widx[34]  = {1, 1, 1,  3, 3, 3, 3, 3,  6, 8,
                           10, 10, 10,  12, 12, 12, 12, 12,  15, 17,
                           19,  21, 21, 21, 21, 21,  24, 26,
                           28, 30, 32, 34, 36, 38};
    const int wcin[34]  = {4, 4, 4,  18, 18, 18, 18, 18,  2, 4,
                           8, 8, 8,  18, 18, 18, 18, 18,  8, 12,
                           16,  18, 18, 18, 18, 18,  16, 14,
                           12, 28, 16, 8, 16, 8};
    const int wcout[34] = {6, 6, 6,  8, 8, 8, 8, 4,  4, 8,
                           6, 6, 6,  8, 8, 8, 8, 4,  12, 16,
                           18,  8, 8, 8, 8, 4,  14, 12,
                           12, 16, 8, 8, 8, 2};
    const int wk2[34]   = {25, 25, 25,  25, 25, 25, 25, 25,  9, 9,
                           25, 25, 25,  25, 25, 25, 25, 25,  9, 9,
                           25,  25, 25, 25, 25, 25,  9, 9,
                           9, 9, 9, 9, 9, 9};
    const int wsoff[34] = {0, 600, 1200,  0, 3600, 7200, 10800, 14400,  0, 0,
                           0, 1200, 2400,  0, 3600, 7200, 10800, 14400,  0, 0,
                           0,  0, 3600, 7200, 10800, 14400,  0, 0,
                           0, 0, 0, 0, 0, 0};
    const int cont[34]  = {1, 1, 0,  1, 1, 1, 0, 0,  0, 0,
                           1, 1, 0,  1, 1, 1, 0, 0,  0, 0,
                           0,  1, 1, 1, 0, 0,  0, 0,
                           0, 0, 0, 0, 0, 0};
    TTab tab;
    const float* tw[40];
    int off = 0, base = 0;
    for (int i = 0; i < 34; ++i) {
        const int n = wcin[i] * wcout[i] * wk2[i];
        tab.e[i].src = (const float*)d_in[widx[i]] + wsoff[i];
        tab.e[i].dst = off; tab.e[i].cin = wcin[i]; tab.e[i].cout = wcout[i];
        tab.e[i].k2 = wk2[i]; tab.e[i].base = base; tab.e[i].n = n;
        tw[i] = wsf + off;
        off = cont[i] ? (off + n) : ((off + n + 63) & ~63);
        base += n;
    }
    const int didx[3]   = {5, 14, 23};
    const int dcoutg[3] = {1, 4, 8};
    const int dcpg[3]   = {2, 4, 8};
    for (int i = 0; i < 3; ++i) {
        for (int g = 0; g < 2; ++g) {
            const int e = 34 + 2 * i + g;
            const int n = dcoutg[i] * dcpg[i] * 9;
            tab.e[e].src = (const float*)d_in[didx[i]] + (size_t)g * n;
            tab.e[e].dst = off; tab.e[e].cin = dcpg[i]; tab.e[e].cout = dcoutg[i];
            tab.e[e].k2 = 9; tab.e[e].base = base; tab.e[e].n = n;
            tw[e] = wsf + off;
            off = (off + n + 63) & ~63;
            base += n;
        }
    }
    tab.total = base;
    transpose_w_k<<<(base + THREADS - 1) / THREADS, THREADS, 0, stream>>>(tab, wsf);

    int B = 4;
    while (B > 1 && ws_size < ((size_t)TW_FLOATS + (size_t)B * SLOT) * sizeof(float)) B >>= 1;

    auto run_all = [&](int Bc, float* slot, int SB,
                       const float* xin, int xbs, float* outp, int obs) {
        float* S0 = slot;                // 36*A1
        float* S1 = S0 + 36 * A1;        // 18*A1
        float* S2 = S1 + 18 * A1;        //  2*A1
        float* P  = S2 + 2 * A1;         //  2*A1
        float* L1 = S1 + 10 * A1;        //  8*A1 tail of S1 (conv1_d skip)
        float* L2 = S0 + 32 * A1;        //  4*A1 tail of S0 (conv2_d skip)
        // sliced conv: 1-D grid, z fastest, pixel-block slowest
        auto gs = [&](int n, int px, int z) { return dim3((n / (px * THREADS)) * Bc * z); };
        auto gp = [&](int n, int px) { return dim3(n / (px * THREADS), Bc); };
        auto g1 = [&](int n) { return dim3((n + THREADS - 1) / THREADS, Bc); };

        // ---- level 1 down ----
        conv_sl_k<4, 6, 5, false, 8><<<gs(A1, 8, 3), THREADS, 0, stream>>>(xin, tw[0], eo1_b1, S1, H1, 9, xbs, SB, Bc, 3);
        conv_sl_k<18, 8, 5, false, 8><<<gs(A1, 8, 4), THREADS, 0, stream>>>(S1, tw[3], eo1_b2, S0, H1, 9, SB, SB, Bc, 4);
        conv_sl_k<18, 4, 5, false, 8><<<gs(A1, 8, 1), THREADS, 0, stream>>>(S1, tw[7], eo1_b2 + 32, S0 + 32 * A1, H1, 9, SB, SB, Bc, 1);
        dconv_k<4, 2><<<g1(A1), THREADS, 0, stream>>>(xin, S0, tw[34], tw[35], S2, H1, 9, xbs, SB, SB);
        conv_k<2, 4, 3, true, 4><<<gp(A1, 4), THREADS, 0, stream>>>(S2, tw[8], c1d_b1, S1, H1, 9, SB, SB);
        conv_k<4, 8, 3, true, 4><<<gp(A1, 4), THREADS, 0, stream>>>(S1, tw[9], c1d_b2, L1, H1, 9, SB, SB);
        avgpool_k<<<g1(8 * A2), THREADS, 0, stream>>>(L1, P, 8 * A2, 16, 8, SB, SB);

        // ---- level 2 down ----
        conv_sl_k<8, 6, 5, false, 8><<<gs(A2, 8, 3), THREADS, 0, stream>>>(P, tw[10], eo2_b1, S1, H2, 8, SB, SB, Bc, 3);
        conv_sl_k<18, 8, 5, false, 8><<<gs(A2, 8, 4), THREADS, 0, stream>>>(S1, tw[13], eo2_b2, S0, H2, 8, SB, SB, Bc, 4);
        conv_sl_k<18, 4, 5, false, 8><<<gs(A2, 8, 1), THREADS, 0, stream>>>(S1, tw[17], eo2_b2 + 32, S0 + 32 * A2, H2, 8, SB, SB, Bc, 1);
        dconv_k<8, 8><<<g1(A2), THREADS, 0, stream>>>(P, S0, tw[36], tw[37], S2, H2, 8, SB, SB, SB);
        conv_k<8, 12, 3, true, 2><<<gp(A2, 2), THREADS, 0, stream>>>(S2, tw[18], c2d_b1, S1, H2, 8, SB, SB);
        conv_k<12, 16, 3, true, 2><<<gp(A2, 2), THREADS, 0, stream>>>(S1, tw[19], c2d_b2, L2, H2, 8, SB, SB);
        avgpool_k<<<g1(16 * A3), THREADS, 0, stream>>>(L2, P, 16 * A3, 14, 7, SB, SB);

        // ---- level 3 (bottleneck) ----
        conv_k<16, 18, 5, false, 2><<<gp(A3, 2), THREADS, 0, stream>>>(P, tw[20], eo3_b1, S1, H3, 7, SB, SB);
        conv_sl_k<18, 8, 5, false, 4><<<gs(A3, 4, 4), THREADS, 0, stream>>>(S1, tw[21], eo3_b2, S0, H3, 7, SB, SB, Bc, 4);
        conv_sl_k<18, 4, 5, false, 4><<<gs(A3, 4, 1), THREADS, 0, stream>>>(S1, tw[25], eo3_b2 + 32, S0 + 32 * A3, H3, 7, SB, SB, Bc, 1);
        dconv_k<16, 16><<<g1(A3), THREADS, 0, stream>>>(P, S0, tw[38], tw[39], S2, H3, 7, SB, SB, SB);
        conv_k<16, 14, 3, true, 2><<<gp(A3, 2), THREADS, 0, stream>>>(S2, tw[26], c3d_b1, S1, H3, 7, SB, SB);
        conv_k<14, 12, 3, true, 2><<<gp(A3, 2), THREADS, 0, stream>>>(S1, tw[27], c3d_b2, S2, H3, 7, SB, SB);

        // ---- up path level 2 ----
        up2x_k<<<g1(12 * A2), THREADS, 0, stream>>>(S2, S0, 12 * A2, 16, 8, H3, SB, SB);
        conv_k<12, 12, 3, true, 2><<<gp(A2, 2), THREADS, 0, stream>>>(S0, tw[28], up2_b, S1, H2, 8, SB, SB);
        copy_k<<<g1(4 * A2), THREADS, 0, stream>>>((float4*)(S1 + 12 * A2), (const float4*)L2,
                                                   4 * A2, SB / 4, SB / 4);
        conv_k<28, 16, 3, true, 2><<<gp(A2, 2), THREADS, 0, stream>>>(S1, tw[29], c2u_b1, S0, H2, 8, SB, SB);
        conv_k<16, 8, 3, true, 2><<<gp(A2, 2), THREADS, 0, stream>>>(S0, tw[30], c2u_b2, S2, H2, 8, SB, SB);

        // ---- up path level 1 ----
        up2x_k<<<g1(8 * A1), THREADS, 0, stream>>>(S2, S0, 8 * A1, 18, 9, H2, SB, SB);
        conv_k<8, 8, 3, true, 4><<<gp(A1, 4), THREADS, 0, stream>>>(S0, tw[31], up1_b, S0 + 8 * A1, H1, 9, SB, SB);
        copy_k<<<g1(2 * A1), THREADS, 0, stream>>>((float4*)(S0 + 16 * A1), (const float4*)L1,
                                                   2 * A1, SB / 4, SB / 4);
        conv_k<16, 8, 3, true, 4><<<gp(A1, 4), THREADS, 0, stream>>>(S0 + 8 * A1, tw[32], c1u_b1, S1, H1, 9, SB, SB);
        conv_k<8, 2, 3, true, 4><<<gp(A1, 4), THREADS, 0, stream>>>(S1, tw[33], c1u_b2, outp, H1, 9, SB, obs);
    };

    for (int g = 0; g < 4; g += B)
        run_all(B, wsf + TW_FLOATS, SLOT,
                x + (size_t)g * 4 * A1, 4 * A1,
                out + (size_t)g * 2 * A1, 2 * A1);
}

// Round 11
// 1528.607 us; speedup vs baseline: 1.8027x; 1.2683x over previous
//
#include <hip/hip_runtime.h>
#include <math.h>

#define THREADS 256
typedef __attribute__((ext_vector_type(2))) float f32x2;
typedef __attribute__((ext_vector_type(4))) float f32x4;

__device__ __forceinline__ float silu_f(float v) {
    return v / (1.f + __expf(-v));
}

// packed fp32 fma (CDNA2+ v_pk_fma_f32), broadcast src0 half via op_sel:
// d.x += a.SEL*b.x ; d.y += a.SEL*b.y   (SEL = lo or hi half of a)
__device__ __forceinline__ void pk_fma_lo(f32x2& d, f32x2 a, f32x2 b) {
    asm("v_pk_fma_f32 %0, %1, %2, %0 op_sel:[0,0,0] op_sel_hi:[0,1,1]"
        : "+v"(d) : "v"(a), "v"(b));
}
__device__ __forceinline__ void pk_fma_hi(f32x2& d, f32x2 a, f32x2 b) {
    asm("v_pk_fma_f32 %0, %1, %2, %0 op_sel:[1,0,0] op_sel_hi:[1,1,1]"
        : "+v"(d) : "v"(a), "v"(b));
}

// ---------------------------------------------------------------------------
// Weight transpose: [co][ci][k2] -> [ci][k2][co]  (co contiguous)
// ---------------------------------------------------------------------------
struct TEnt { const float* src; int dst; int cin; int cout; int k2; int base; int n; };
struct TTab { TEnt e[40]; int total; };

__global__ __launch_bounds__(THREADS)
void transpose_w_k(TTab t, float* __restrict__ tw) {
    const int i = blockIdx.x * THREADS + threadIdx.x;
    if (i >= t.total) return;
    int j = 0;
    while (i >= t.e[j].base + t.e[j].n) ++j;
    const TEnt e = t.e[j];
    const int local = i - e.base;
    const int co  = local % e.cout;
    const int tmp = local / e.cout;
    const int k   = tmp % e.k2;
    const int ci  = tmp / e.k2;
    tw[e.dst + local] = e.src[(co * e.cin + ci) * e.k2 + k];
}

// aligned-chunk row loader with edge fallback
template<int KS, int PX>
__device__ __forceinline__ void load_row(float* __restrict__ rr,
                                         const float* __restrict__ rp,
                                         bool vy, int x0, int W)
{
    constexpr int PAD = (KS - 1) / 2;
    constexpr int RW = PX + KS - 1;
#pragma unroll
    for (int q = -1; q <= PX / 4; ++q) {
        if (4 * q + 3 + PAD < 0 || 4 * q + PAD >= RW) continue;
        const int xs = x0 + 4 * q;
        float vc[4] = {0.f, 0.f, 0.f, 0.f};
        if (vy && xs >= 0 && xs + 4 <= W) {
            const float4 v = *reinterpret_cast<const float4*>(rp + xs);
            vc[0] = v.x; vc[1] = v.y; vc[2] = v.z; vc[3] = v.w;
        } else if (vy) {
#pragma unroll
            for (int c = 0; c < 4; ++c)
                vc[c] = ((unsigned)(xs + c) < (unsigned)W) ? rp[xs + c] : 0.f;
        }
#pragma unroll
        for (int c = 0; c < 4; ++c) {
            const int t = 4 * q + c + PAD;
            if (t >= 0 && t < RW) rr[t] = vc[c];
        }
    }
}

// ---------------------------------------------------------------------------
// Per-channel body for conv_sl_k. PHASE = cl&1 (compile-time) keeps the
// rotating row/weight buffer parities constant-folded (rule-#20: no runtime
// indexed register arrays). Prefetch rotates ACROSS the channel boundary so
// no cold-start stall per cl (round-10 lesson).
// ---------------------------------------------------------------------------
template<int CIN, int COUT, int KS, int PX, int PHASE, int RW2, int WQ, int NP>
__device__ __forceinline__ void chan_body(
    const float* __restrict__ ip0, const float* __restrict__ sw,
    int cl, int y, int x0, int W, int H, int lw, int total,
    f32x2 (&r2)[2][RW2], f32x4 (&wb)[2][WQ], f32x2 (&acc)[NP][PX])
{
    constexpr int PAD = (KS - 1) / 2;
    constexpr int K2 = KS * KS;
    constexpr int CO_S = (COUT + 3) & ~3;
#pragma unroll
    for (int ky = 0; ky < KS; ++ky) {
        // prefetch next row (possibly first row of next channel)
        {
            const bool last = (ky + 1 == KS);
            const int ncl = cl + (last ? 1 : 0);
            const int nky = last ? 0 : (ky + 1);
            if (!last || ncl < CIN) {
                const int yy = y + nky - PAD;
                load_row<KS, PX>((float*)r2[(PHASE + ky + 1) & 1],
                                 ip0 + (size_t)ncl * total + (yy << lw),
                                 (unsigned)yy < (unsigned)H, x0, W);
            }
        }
#pragma unroll
        for (int kx = 0; kx < KS; ++kx) {
            const int t = ky * KS + kx;
            const int wc = (PHASE + t) & 1;
            // prefetch next tap's weights (LDS is [cl][k2][CO_S] contiguous)
            if (t + 1 < K2 || cl + 1 < CIN) {
                const f32x4* __restrict__ nx =
                    (const f32x4*)(sw + (size_t)(cl * K2 + t + 1) * CO_S);
#pragma unroll
                for (int q = 0; q < WQ; ++q) wb[wc ^ 1][q] = nx[q];
            }
#pragma unroll
            for (int q = 0; q < WQ; ++q) {
                const f32x4 w4 = wb[wc][q];
                const f32x2 wlo = __builtin_shufflevector(w4, w4, 0, 1);
                const f32x2 whi = __builtin_shufflevector(w4, w4, 2, 3);
#pragma unroll
                for (int s = 0; s < 2; ++s) {
                    const int p = 2 * q + s;
                    if (p < NP) {
                        const f32x2 wp = s ? whi : wlo;
#pragma unroll
                        for (int j = 0; j < PX; ++j) {
                            const int e = kx + j;
                            if (e & 1) pk_fma_hi(acc[p][j], r2[(PHASE + ky) & 1][e >> 1], wp);
                            else       pk_fma_lo(acc[p][j], r2[(PHASE + ky) & 1][e >> 1], wp);
                        }
                    }
                }
            }
            __builtin_amdgcn_sched_barrier(0);
        }
    }
}

// ---------------------------------------------------------------------------
// Sliced direct conv2d, 1-D grid: lin = z + NZ*(b + NB*xblk)  (z fastest ->
// slices sharing input run back-to-back, L2/L3 reuse; round-9/10 lesson).
// Packed-FMA inner loop (co-pairs), continuous cross-channel prefetch.
// ---------------------------------------------------------------------------
template<int CIN, int COUT, int KS, bool ACT, int PX>
__global__ __launch_bounds__(THREADS)
void conv_sl_k(const float* __restrict__ in, const float* __restrict__ wt,
               const float* __restrict__ bias, float* __restrict__ out,
               int H, int lw, int bs_in, int bs_out, int nb, int nz)
{
    constexpr int PAD = (KS - 1) / 2;
    constexpr int K2 = KS * KS;
    constexpr int CO_S = (COUT + 3) & ~3;
    constexpr int WQ = CO_S / 4;
    constexpr int NP = COUT / 2;
    constexpr int RW = PX + KS - 1;
    constexpr int RW2 = (RW + 1) / 2;
    static_assert(CIN % 2 == 0 && COUT % 2 == 0 && PX % 4 == 0, "");
    __shared__ float sw[CIN * K2 * CO_S];

    int lin = blockIdx.x;
    const int z = lin % nz; lin /= nz;
    const int b = lin % nb; lin /= nb;
    const int xb = lin;

    const float* __restrict__ wz = wt + (size_t)z * (CIN * K2 * COUT);
    const int W = 1 << lw;
    const int total = H << lw;
    const int idx = (xb * THREADS + threadIdx.x) * PX;
    const float* ip0 = in + (size_t)b * bs_in;
    float* op = out + (size_t)b * bs_out + (size_t)z * COUT * total;
    const int x0 = idx & (W - 1);
    const int y  = idx >> lw;

    for (int i = threadIdx.x; i < CIN * K2 * COUT; i += THREADS)
        sw[(i / COUT) * CO_S + i % COUT] = wz[i];
    __syncthreads();

    f32x2 acc[NP][PX];
#pragma unroll
    for (int p = 0; p < NP; ++p) {
        f32x2 bb;
        bb.x = bias[z * COUT + 2 * p];
        bb.y = bias[z * COUT + 2 * p + 1];
#pragma unroll
        for (int j = 0; j < PX; ++j) acc[p][j] = bb;
    }

    f32x2 r2[2][RW2];
    f32x4 wb[2][WQ];
    {
        const int yy = y - PAD;
        load_row<KS, PX>((float*)r2[0], ip0 + (yy << lw),
                         (unsigned)yy < (unsigned)H, x0, W);
        const f32x4* __restrict__ w0 = (const f32x4*)sw;
#pragma unroll
        for (int q = 0; q < WQ; ++q) wb[0][q] = w0[q];
    }

#pragma unroll 1
    for (int c2 = 0; c2 < CIN / 2; ++c2) {
        chan_body<CIN, COUT, KS, PX, 0, RW2, WQ, NP>(ip0, sw, 2 * c2,     y, x0, W, H, lw, total, r2, wb, acc);
        chan_body<CIN, COUT, KS, PX, 1, RW2, WQ, NP>(ip0, sw, 2 * c2 + 1, y, x0, W, H, lw, total, r2, wb, acc);
    }

#pragma unroll
    for (int p = 0; p < NP; ++p) {
#pragma unroll
        for (int h = 0; h < 2; ++h) {
            const int co = 2 * p + h;
#pragma unroll
            for (int j4 = 0; j4 < PX / 4; ++j4) {
                float4 v;
                float a0 = h ? acc[p][4 * j4 + 0].y : acc[p][4 * j4 + 0].x;
                float a1 = h ? acc[p][4 * j4 + 1].y : acc[p][4 * j4 + 1].x;
                float a2 = h ? acc[p][4 * j4 + 2].y : acc[p][4 * j4 + 2].x;
                float a3 = h ? acc[p][4 * j4 + 3].y : acc[p][4 * j4 + 3].x;
                v.x = ACT ? silu_f(a0) : a0;
                v.y = ACT ? silu_f(a1) : a1;
                v.z = ACT ? silu_f(a2) : a2;
                v.w = ACT ? silu_f(a3) : a3;
                *reinterpret_cast<float4*>(op + (size_t)co * total + idx + 4 * j4) = v;
            }
        }
    }
}

// ---------------------------------------------------------------------------
// Generic direct conv2d (packed-FMA inner loop), grid.y = batch.
// ---------------------------------------------------------------------------
template<int CIN, int COUT, int KS, bool ACT, int PX>
__global__ __launch_bounds__(THREADS)
void conv_k(const float* __restrict__ in, const float* __restrict__ wt,
            const float* __restrict__ bias, float* __restrict__ out,
            int H, int lw, int bs_in, int bs_out)
{
    constexpr int PAD = (KS - 1) / 2;
    constexpr int K2 = KS * KS;
    constexpr int CO_S = (COUT + 3) & ~3;
    constexpr int WQ = CO_S / 4;
    constexpr int NP = COUT / 2;
    constexpr int RW = PX + KS - 1;
    constexpr int RW2 = (RW + 1) / 2;
    static_assert(COUT % 2 == 0, "");
    __shared__ float sw[CIN * K2 * CO_S];

    const int W = 1 << lw;
    const int total = H << lw;
    const int idx = (blockIdx.x * THREADS + threadIdx.x) * PX;
    const float* ip0 = in + (size_t)blockIdx.y * bs_in;
    float* op = out + (size_t)blockIdx.y * bs_out;
    const int x0 = idx & (W - 1);
    const int y  = idx >> lw;

    for (int i = threadIdx.x; i < CIN * K2 * COUT; i += THREADS)
        sw[(i / COUT) * CO_S + i % COUT] = wt[i];
    __syncthreads();

    f32x2 acc[NP][PX];
#pragma unroll
    for (int p = 0; p < NP; ++p) {
        f32x2 bb;
        bb.x = bias[2 * p];
        bb.y = bias[2 * p + 1];
#pragma unroll
        for (int j = 0; j < PX; ++j) acc[p][j] = bb;
    }

#pragma unroll 1
    for (int cl = 0; cl < CIN; ++cl) {
        const float* __restrict__ row0 = ip0 + (size_t)cl * total;
        f32x2 r2[KS][RW2];
#pragma unroll
        for (int ky = 0; ky < KS; ++ky) {
            const int yy = y + ky - PAD;
            load_row<KS, PX>((float*)r2[ky], row0 + (yy << lw),
                             (unsigned)yy < (unsigned)H, x0, W);
        }
        const float* __restrict__ wbase = &sw[cl * K2 * CO_S];
#pragma unroll
        for (int t = 0; t < K2; ++t) {
            const int ky = t / KS, kx = t % KS;
            const f32x4* __restrict__ wv = (const f32x4*)(wbase + t * CO_S);
#pragma unroll
            for (int q = 0; q < WQ; ++q) {
                const f32x4 w4 = wv[q];
                const f32x2 wlo = __builtin_shufflevector(w4, w4, 0, 1);
                const f32x2 whi = __builtin_shufflevector(w4, w4, 2, 3);
#pragma unroll
                for (int s = 0; s < 2; ++s) {
                    const int p = 2 * q + s;
                    if (p < NP) {
                        const f32x2 wp = s ? whi : wlo;
#pragma unroll
                        for (int j = 0; j < PX; ++j) {
                            const int e = kx + j;
                            if (e & 1) pk_fma_hi(acc[p][j], r2[ky][e >> 1], wp);
                            else       pk_fma_lo(acc[p][j], r2[ky][e >> 1], wp);
                        }
                    }
                }
            }
            __builtin_amdgcn_sched_barrier(0);
        }
    }

#pragma unroll
    for (int p = 0; p < NP; ++p) {
#pragma unroll
        for (int h = 0; h < 2; ++h) {
            const int co = 2 * p + h;
            if (PX == 2) {
                float2 v;
                float a0 = h ? acc[p][0].y : acc[p][0].x;
                float a1 = h ? acc[p][1].y : acc[p][1].x;
                v.x = ACT ? silu_f(a0) : a0;
                v.y = ACT ? silu_f(a1) : a1;
                *reinterpret_cast<float2*>(op + (size_t)co * total + idx) = v;
            } else {
#pragma unroll
                for (int j4 = 0; j4 < PX / 4; ++j4) {
                    float4 v;
                    float a0 = h ? acc[p][4 * j4 + 0].y : acc[p][4 * j4 + 0].x;
                    float a1 = h ? acc[p][4 * j4 + 1].y : acc[p][4 * j4 + 1].x;
                    float a2 = h ? acc[p][4 * j4 + 2].y : acc[p][4 * j4 + 2].x;
                    float a3 = h ? acc[p][4 * j4 + 3].y : acc[p][4 * j4 + 3].x;
                    v.x = ACT ? silu_f(a0) : a0;
                    v.y = ACT ? silu_f(a1) : a1;
                    v.z = ACT ? silu_f(a2) : a2;
                    v.w = ACT ? silu_f(a3) : a3;
                    *reinterpret_cast<float4*>(op + (size_t)co * total + idx + 4 * j4) = v;
                }
            }
        }
    }
}

// ---------------------------------------------------------------------------
// DeformConv2d: 3x3, stride 1, pad 1, no bias. groups=2, offset groups=2.
// ---------------------------------------------------------------------------
template<int CIN, int COUT>
__global__ __launch_bounds__(THREADS)
void dconv_k(const float* __restrict__ in, const float* __restrict__ off,
             const float* __restrict__ twg0, const float* __restrict__ twg1,
             float* __restrict__ out,
             int H, int lw, int bs_in, int bs_off, int bs_out)
{
    constexpr int K = 9;
    constexpr int OG = 2;
    constexpr int COG = CIN / OG;
    constexpr int COUTG = COUT / 2;
    constexpr int NWG = COG * K * COUTG;
    __shared__ float sw[2 * NWG];
    for (int i = threadIdx.x; i < 2 * NWG; i += THREADS)
        sw[i] = (i < NWG) ? twg0[i] : twg1[i - NWG];
    __syncthreads();

    const int W = 1 << lw;
    const int total = H << lw;
    const int idx = blockIdx.x * THREADS + threadIdx.x;
    const float* ip0 = in + (size_t)blockIdx.y * bs_in;
    const float* offp = off + (size_t)blockIdx.y * bs_off;
    float* op = out + (size_t)blockIdx.y * bs_out;
    const int x = idx & (W - 1);
    const int y = idx >> lw;

    float acc[COUT];
#pragma unroll
    for (int co = 0; co < COUT; ++co) acc[co] = 0.f;

#pragma unroll
    for (int og = 0; og < OG; ++og) {
#pragma unroll
        for (int k = 0; k < K; ++k) {
            const int ki = k / 3 - 1;
            const int kj = k % 3 - 1;
            const float dy = offp[(size_t)(((og * K + k) * 2 + 0)) * total + idx];
            const float dx = offp[(size_t)(((og * K + k) * 2 + 1)) * total + idx];
            const float py = dy + (float)(y + ki);
            const float px = dx + (float)(x + kj);
            const float y0f = floorf(py), x0f = floorf(px);
            const float ly = py - y0f, lx = px - x0f;
            const int y0 = (int)y0f, x0 = (int)x0f;
            const int y1 = y0 + 1, x1 = x0 + 1;
            const bool vy0 = (unsigned)y0 < (unsigned)H;
            const bool vy1 = (unsigned)y1 < (unsigned)H;
            const bool vx0 = (unsigned)x0 < (unsigned)W;
            const bool vx1 = (unsigned)x1 < (unsigned)W;
            const int cy0 = min(max(y0, 0), H - 1), cy1 = min(max(y1, 0), H - 1);
            const int cx0 = min(max(x0, 0), W - 1), cx1 = min(max(x1, 0), W - 1);
            const int i00 = (cy0 << lw) + cx0, i01 = (cy0 << lw) + cx1;
            const int i10 = (cy1 << lw) + cx0, i11 = (cy1 << lw) + cx1;
            const float f00 = (vy0 && vx0) ? (1.f - ly) * (1.f - lx) : 0.f;
            const float f01 = (vy0 && vx1) ? (1.f - ly) * lx : 0.f;
            const float f10 = (vy1 && vx0) ? ly * (1.f - lx) : 0.f;
            const float f11 = (vy1 && vx1) ? ly * lx : 0.f;
            const float* swg = &sw[og * NWG];
#pragma unroll
            for (int c = 0; c < COG; ++c) {
                const float* __restrict__ ip = ip0 + (size_t)(og * COG + c) * total;
                const float v = f00 * ip[i00] + f01 * ip[i01]
                              + f10 * ip[i10] + f11 * ip[i11];
                const float* __restrict__ wr = &swg[(c * K + k) * COUTG];
#pragma unroll
                for (int col = 0; col < COUTG; ++col)
                    acc[og * COUTG + col] = fmaf(v, wr[col], acc[og * COUTG + col]);
            }
        }
    }

#pragma unroll
    for (int co = 0; co < COUT; ++co)
        op[(size_t)co * total + idx] = acc[co];
}

// 2x2 average pool.
__global__ __launch_bounds__(THREADS)
void avgpool_k(const float* __restrict__ in, float* __restrict__ out,
               int n, int lt, int lwo, int bsi, int bso)
{
    const int idx = blockIdx.x * THREADS + threadIdx.x;
    if (idx >= n) return;
    const float* ip0 = in + (size_t)blockIdx.y * bsi;
    float* op = out + (size_t)blockIdx.y * bso;
    const int c = idx >> lt;
    const int r = idx & ((1 << lt) - 1);
    const int oy = r >> lwo;
    const int ox = r & ((1 << lwo) - 1);
    const int Wi = 2 << lwo;
    const float* ip = ip0 + ((size_t)c << (lt + 2)) + ((size_t)(2 * oy) << (lwo + 1)) + 2 * ox;
    const float2 t = *reinterpret_cast<const float2*>(ip);
    const float2 b = *reinterpret_cast<const float2*>(ip + Wi);
    op[idx] = 0.25f * (t.x + t.y + b.x + b.y);
}

// Bilinear 2x upsample, align_corners=True.
__global__ __launch_bounds__(THREADS)
void up2x_k(const float* __restrict__ in, float* __restrict__ out,
            int n, int lt, int lwo, int Hin, int bsi, int bso)
{
    const int idx = blockIdx.x * THREADS + threadIdx.x;
    if (idx >= n) return;
    const float* ip0 = in + (size_t)blockIdx.y * bsi;
    float* op = out + (size_t)blockIdx.y * bso;
    const int c = idx >> lt;
    const int r = idx & ((1 << lt) - 1);
    const int oy = r >> lwo;
    const int ox = r & ((1 << lwo) - 1);
    const int W = 1 << (lwo - 1);
    const int H = Hin;
    const float s = (float)(H - 1) / (float)(2 * H - 1);
    const float fy = (float)oy * s;
    const float fx = (float)ox * s;
    const int y0 = (int)fy;
    const int x0 = (int)fx;
    const int y1 = min(y0 + 1, H - 1);
    const int x1 = min(x0 + 1, W - 1);
    const float wy = fy - (float)y0;
    const float wx = fx - (float)x0;
    const float* ip = ip0 + ((size_t)c << (lt - 2));
    const float v00 = ip[y0 * W + x0], v01 = ip[y0 * W + x1];
    const float v10 = ip[y1 * W + x0], v11 = ip[y1 * W + x1];
    op[idx] = (v00 * (1.f - wy) + v10 * wy) * (1.f - wx)
            + (v01 * (1.f - wy) + v11 * wy) * wx;
}

// strided batched d2d copy (float4 granularity)
__global__ __launch_bounds__(THREADS)
void copy_k(float4* __restrict__ dst, const float4* __restrict__ src,
            int n4, int bsd, int bss)
{
    const int i = blockIdx.x * THREADS + threadIdx.x;
    if (i >= n4) return;
    dst[(size_t)blockIdx.y * bsd + i] = src[(size_t)blockIdx.y * bss + i];
}

// ---------------------------------------------------------------------------

extern "C" void kernel_launch(void* const* d_in, const int* in_sizes, int n_in,
                              void* d_out, int out_size, void* d_ws, size_t ws_size,
                              hipStream_t stream) {
    const float* x      = (const float*)d_in[0];
    const float* eo1_b1 = (const float*)d_in[2];
    const float* eo1_b2 = (const float*)d_in[4];
    const float* c1d_b1 = (const float*)d_in[7];
    const float* c1d_b2 = (const float*)d_in[9];
    const float* eo2_b1 = (const float*)d_in[11];
    const float* eo2_b2 = (const float*)d_in[13];
    const float* c2d_b1 = (const float*)d_in[16];
    const float* c2d_b2 = (const float*)d_in[18];
    const float* eo3_b1 = (const float*)d_in[20];
    const float* eo3_b2 = (const float*)d_in[22];
    const float* c3d_b1 = (const float*)d_in[25];
    const float* c3d_b2 = (const float*)d_in[27];
    const float* up2_b  = (const float*)d_in[29];
    const float* c2u_b1 = (const float*)d_in[31];
    const float* c2u_b2 = (const float*)d_in[33];
    const float* up1_b  = (const float*)d_in[35];
    const float* c1u_b1 = (const float*)d_in[37];
    const float* c1u_b2 = (const float*)d_in[39];

    float* out = (float*)d_out;
    float* wsf = (float*)d_ws;

    constexpr int H1 = 512, A1 = H1 * H1;
    constexpr int H2 = 256, A2 = H2 * H2;
    constexpr int H3 = 128, A3 = H3 * H3;
    constexpr int TW_FLOATS = 81920;
    constexpr int SLOT = 58 * A1;

    // ---- transposed-weight table: 34 conv entries + 6 dconv groups ----
    const int widx[34]  = {1, 1, 1,  3, 3, 3, 3, 3,  6, 8,
                           10, 10, 10,  12, 12, 12, 12, 12,  15, 17,
                           19,  21, 21, 21, 21, 21,  24, 26,
                           28, 30, 32, 34, 36, 38};
    const int wcin[34]  = {4, 4, 4,  18, 18, 18, 18, 18,  2, 4,
                           8, 8, 8,  18, 18, 18, 18, 18,  8, 12,
                           16,  18, 18, 18, 18, 18,  16, 14,
                           12, 28, 16, 8, 16, 8};
    const int wcout[34] = {6, 6, 6,  8, 8, 8, 8, 4,  4, 8,
                           6, 6, 6,  8, 8, 8, 8, 4,  12, 16,
                           18,  8, 8, 8, 8, 4,  14, 12,
                           12, 16, 8, 8, 8, 2};
    const int wk2[34]   = {25, 25, 25,  25, 25, 25, 25, 25,  9, 9,
                           25, 25, 25,  25, 25, 25, 25, 25,  9, 9,
                           25,  25, 25, 25, 25, 25,  9, 9,
                           9, 9, 9, 9, 9, 9};
    const int wsoff[34] = {0, 600, 1200,  0, 3600, 7200, 10800, 14400,  0, 0,
                           0, 1200, 2400,  0, 3600, 7200, 10800, 14400,  0, 0,
                           0,  0, 3600, 7200, 10800, 14400,  0, 0,
                           0, 0, 0, 0, 0, 0};
    const int cont[34]  = {1, 1, 0,  1, 1, 1, 0, 0,  0, 0,
                           1, 1, 0,  1, 1, 1, 0, 0,  0, 0,
                           0,  1, 1, 1, 0, 0,  0, 0,
                           0, 0, 0, 0, 0, 0};
    TTab tab;
    const float* tw[40];
    int off = 0, base = 0;
    for (int i = 0; i < 34; ++i) {
        const int n = wcin[i] * wcout[i] * wk2[i];
        tab.e[i].src = (const float*)d_in[widx[i]] + wsoff[i];
        tab.e[i].dst = off; tab.e[i].cin = wcin[i]; tab.e[i].cout = wcout[i];
        tab.e[i].k2 = wk2[i]; tab.e[i].base = base; tab.e[i].n = n;
        tw[i] = wsf + off;
        off = cont[i] ? (off + n) : ((off + n + 63) & ~63);
        base += n;
    }
    const int didx[3]   = {5, 14, 23};
    const int dcoutg[3] = {1, 4, 8};
    const int dcpg[3]   = {2, 4, 8};
    for (int i = 0; i < 3; ++i) {
        for (int g = 0; g < 2; ++g) {
            const int e = 34 + 2 * i + g;
            const int n = dcoutg[i] * dcpg[i] * 9;
            tab.e[e].src = (const float*)d_in[didx[i]] + (size_t)g * n;
            tab.e[e].dst = off; tab.e[e].cin = dcpg[i]; tab.e[e].cout = dcoutg[i];
            tab.e[e].k2 = 9; tab.e[e].base = base; tab.e[e].n = n;
            tw[e] = wsf + off;
            off = (off + n + 63) & ~63;
            base += n;
        }
    }
    tab.total = base;
    transpose_w_k<<<(base + THREADS - 1) / THREADS, THREADS, 0, stream>>>(tab, wsf);

    int B = 4;
    while (B > 1 && ws_size < ((size_t)TW_FLOATS + (size_t)B * SLOT) * sizeof(float)) B >>= 1;

    auto run_all = [&](int Bc, float* slot, int SB,
                       const float* xin, int xbs, float* outp, int obs) {
        float* S0 = slot;
        float* S1 = S0 + 36 * A1;
        float* S2 = S1 + 18 * A1;
        float* P  = S2 + 2 * A1;
        float* L1 = S1 + 10 * A1;
        float* L2 = S0 + 32 * A1;
        auto gs = [&](int n, int px, int z) { return dim3((n / (px * THREADS)) * Bc * z); };
        auto gp = [&](int n, int px) { return dim3(n / (px * THREADS), Bc); };
        auto g1 = [&](int n) { return dim3((n + THREADS - 1) / THREADS, Bc); };

        // ---- level 1 down ----
        conv_sl_k<4, 6, 5, false, 8><<<gs(A1, 8, 3), THREADS, 0, stream>>>(xin, tw[0], eo1_b1, S1, H1, 9, xbs, SB, Bc, 3);
        conv_sl_k<18, 8, 5, false, 8><<<gs(A1, 8, 4), THREADS, 0, stream>>>(S1, tw[3], eo1_b2, S0, H1, 9, SB, SB, Bc, 4);
        conv_sl_k<18, 4, 5, false, 8><<<gs(A1, 8, 1), THREADS, 0, stream>>>(S1, tw[7], eo1_b2 + 32, S0 + 32 * A1, H1, 9, SB, SB, Bc, 1);
        dconv_k<4, 2><<<g1(A1), THREADS, 0, stream>>>(xin, S0, tw[34], tw[35], S2, H1, 9, xbs, SB, SB);
        conv_k<2, 4, 3, true, 4><<<gp(A1, 4), THREADS, 0, stream>>>(S2, tw[8], c1d_b1, S1, H1, 9, SB, SB);
        conv_k<4, 8, 3, true, 4><<<gp(A1, 4), THREADS, 0, stream>>>(S1, tw[9], c1d_b2, L1, H1, 9, SB, SB);
        avgpool_k<<<g1(8 * A2), THREADS, 0, stream>>>(L1, P, 8 * A2, 16, 8, SB, SB);

        // ---- level 2 down ----
        conv_sl_k<8, 6, 5, false, 8><<<gs(A2, 8, 3), THREADS, 0, stream>>>(P, tw[10], eo2_b1, S1, H2, 8, SB, SB, Bc, 3);
        conv_sl_k<18, 8, 5, false, 8><<<gs(A2, 8, 4), THREADS, 0, stream>>>(S1, tw[13], eo2_b2, S0, H2, 8, SB, SB, Bc, 4);
        conv_sl_k<18, 4, 5, false, 8><<<gs(A2, 8, 1), THREADS, 0, stream>>>(S1, tw[17], eo2_b2 + 32, S0 + 32 * A2, H2, 8, SB, SB, Bc, 1);
        dconv_k<8, 8><<<g1(A2), THREADS, 0, stream>>>(P, S0, tw[36], tw[37], S2, H2, 8, SB, SB, SB);
        conv_k<8, 12, 3, true, 2><<<gp(A2, 2), THREADS, 0, stream>>>(S2, tw[18], c2d_b1, S1, H2, 8, SB, SB);
        conv_k<12, 16, 3, true, 2><<<gp(A2, 2), THREADS, 0, stream>>>(S1, tw[19], c2d_b2, L2, H2, 8, SB, SB);
        avgpool_k<<<g1(16 * A3), THREADS, 0, stream>>>(L2, P, 16 * A3, 14, 7, SB, SB);

        // ---- level 3 (bottleneck) ----
        conv_k<16, 18, 5, false, 2><<<gp(A3, 2), THREADS, 0, stream>>>(P, tw[20], eo3_b1, S1, H3, 7, SB, SB);
        conv_sl_k<18, 8, 5, false, 4><<<gs(A3, 4, 4), THREADS, 0, stream>>>(S1, tw[21], eo3_b2, S0, H3, 7, SB, SB, Bc, 4);
        conv_sl_k<18, 4, 5, false, 4><<<gs(A3, 4, 1), THREADS, 0, stream>>>(S1, tw[25], eo3_b2 + 32, S0 + 32 * A3, H3, 7, SB, SB, Bc, 1);
        dconv_k<16, 16><<<g1(A3), THREADS, 0, stream>>>(P, S0, tw[38], tw[39], S2, H3, 7, SB, SB, SB);
        conv_k<16, 14, 3, true, 2><<<gp(A3, 2), THREADS, 0, stream>>>(S2, tw[26], c3d_b1, S1, H3, 7, SB, SB);
        conv_k<14, 12, 3, true, 2><<<gp(A3, 2), THREADS, 0, stream>>>(S1, tw[27], c3d_b2, S2, H3, 7, SB, SB);

        // ---- up path level 2 ----
        up2x_k<<<g1(12 * A2), THREADS, 0, stream>>>(S2, S0, 12 * A2, 16, 8, H3, SB, SB);
        conv_k<12, 12, 3, true, 2><<<gp(A2, 2), THREADS, 0, stream>>>(S0, tw[28], up2_b, S1, H2, 8, SB, SB);
        copy_k<<<g1(4 * A2), THREADS, 0, stream>>>((float4*)(S1 + 12 * A2), (const float4*)L2,
                                                   4 * A2, SB / 4, SB / 4);
        conv_k<28, 16, 3, true, 2><<<gp(A2, 2), THREADS, 0, stream>>>(S1, tw[29], c2u_b1, S0, H2, 8, SB, SB);
        conv_k<16, 8, 3, true, 2><<<gp(A2, 2), THREADS, 0, stream>>>(S0, tw[30], c2u_b2, S2, H2, 8, SB, SB);

        // ---- up path level 1 ----
        up2x_k<<<g1(8 * A1), THREADS, 0, stream>>>(S2, S0, 8 * A1, 18, 9, H2, SB, SB);
        conv_k<8, 8, 3, true, 4><<<gp(A1, 4), THREADS, 0, stream>>>(S0, tw[31], up1_b, S0 + 8 * A1, H1, 9, SB, SB);
        copy_k<<<g1(2 * A1), THREADS, 0, stream>>>((float4*)(S0 + 16 * A1), (const float4*)L1,
                                                   2 * A1, SB / 4, SB / 4);
        conv_k<16, 8, 3, true, 4><<<gp(A1, 4), THREADS, 0, stream>>>(S0 + 8 * A1, tw[32], c1u_b1, S1, H1, 9, SB, SB);
        conv_k<8, 2, 3, true, 4><<<gp(A1, 4), THREADS, 0, stream>>>(S1, tw[33], c1u_b2, outp, H1, 9, SB, obs);
    };

    for (int g = 0; g < 4; g += B)
        run_all(B, wsf + TW_FLOATS, SLOT,
                x + (size_t)g * 4 * A1, 4 * A1,
                out + (size_t)g * 2 * A1, 2 * A1);
}